// Round 2
// baseline (2447.258 us; speedup 1.0000x reference)
//
#include <hip/hip_runtime.h>

typedef __attribute__((ext_vector_type(8))) short bf16x8;
typedef __attribute__((ext_vector_type(4))) float f32x4;

#define B_SZ   64
#define IMGSZ  12288            // 3*64*64
#define DENC   26176
#define ENC_H  800
#define DEC_H  1600
#define NZ     100
#define NENC   6400             // 4*ENC_H*2 (mu ++ lv)
#define KENC   13888            // 12288 (sb) + 1600 (h_dec)
#define KWB    12288
#define KDEC   1728             // 1600 + 100 + 28 pad
#define GSZ    (B_SZ*NENC)
#define NSL    16

__device__ __forceinline__ unsigned short f2bf(float f){
  unsigned u = __float_as_uint(f);
  u += 0x7fffu + ((u >> 16) & 1u);
  return (unsigned short)(u >> 16);
}
__device__ __forceinline__ float bf2f(unsigned short h){
  return __uint_as_float(((unsigned)h) << 16);
}
__device__ __forceinline__ float sigf(float x){ return 1.f/(1.f + __expf(-x)); }
__device__ __forceinline__ ushort4 cv4(float4 v){
  ushort4 o; o.x=f2bf(v.x); o.y=f2bf(v.y); o.z=f2bf(v.z); o.w=f2bf(v.w); return o;
}
__device__ __forceinline__ bf16x8 pk8(float4 a, float4 b){
  bf16x8 r;
  r[0]=(short)f2bf(a.x); r[1]=(short)f2bf(a.y); r[2]=(short)f2bf(a.z); r[3]=(short)f2bf(a.w);
  r[4]=(short)f2bf(b.x); r[5]=(short)f2bf(b.y); r[6]=(short)f2bf(b.z); r[7]=(short)f2bf(b.w);
  return r;
}

// ---- GEMM core: acc += A[64 x K-slice] * B[cols x K-slice]^T ----
template<int NF, int BF32>
__device__ __forceinline__ void gemm_acc(const unsigned short* __restrict__ A, int lda,
                                         const void* __restrict__ Bv, int ldb,
                                         int k0, int k1, int nrow0,
                                         f32x4 acc[4][NF])
{
  const int lane = threadIdx.x & 63;
  const int wave = threadIdx.x >> 6;
  const int l15 = lane & 15, lg = lane >> 4;

  const unsigned short* pA = A + (size_t)l15*lda + k0 + lg*8;
#pragma unroll
  for (int m = 0; m < 4; ++m)
#pragma unroll
    for (int f = 0; f < NF; ++f)
      acc[m][f] = (f32x4){0.f,0.f,0.f,0.f};

  if (BF32){
    const float* pB[NF];
#pragma unroll
    for (int f = 0; f < NF; ++f)
      pB[f] = (const float*)Bv + (size_t)(nrow0 + wave*(NF*16) + f*16 + l15)*ldb + k0 + lg*8;
    int k = k0;
    for (; k + 64 <= k1; k += 64){
      float4 c00[NF], c01[NF], c10[NF], c11[NF];
      bf16x8 a0[4], a1[4];
#pragma unroll
      for (int f = 0; f < NF; ++f){
        c00[f] = *(const float4*)(pB[f]);      c01[f] = *(const float4*)(pB[f]+4);
        c10[f] = *(const float4*)(pB[f]+32);   c11[f] = *(const float4*)(pB[f]+36);
        pB[f] += 64;
      }
#pragma unroll
      for (int m = 0; m < 4; ++m){
        const unsigned short* p = pA + (size_t)m*16*lda;
        a0[m] = *(const bf16x8*)(p); a1[m] = *(const bf16x8*)(p+32);
      }
      pA += 64;
#pragma unroll
      for (int m = 0; m < 4; ++m)
#pragma unroll
        for (int f = 0; f < NF; ++f)
          acc[m][f] = __builtin_amdgcn_mfma_f32_16x16x32_bf16(a0[m], pk8(c00[f],c01[f]), acc[m][f], 0,0,0);
#pragma unroll
      for (int m = 0; m < 4; ++m)
#pragma unroll
        for (int f = 0; f < NF; ++f)
          acc[m][f] = __builtin_amdgcn_mfma_f32_16x16x32_bf16(a1[m], pk8(c10[f],c11[f]), acc[m][f], 0,0,0);
    }
    if (k < k1){
      float4 c00[NF], c01[NF]; bf16x8 a0[4];
#pragma unroll
      for (int f = 0; f < NF; ++f){ c00[f] = *(const float4*)(pB[f]); c01[f] = *(const float4*)(pB[f]+4); }
#pragma unroll
      for (int m = 0; m < 4; ++m) a0[m] = *(const bf16x8*)(pA + (size_t)m*16*lda);
#pragma unroll
      for (int m = 0; m < 4; ++m)
#pragma unroll
        for (int f = 0; f < NF; ++f)
          acc[m][f] = __builtin_amdgcn_mfma_f32_16x16x32_bf16(a0[m], pk8(c00[f],c01[f]), acc[m][f], 0,0,0);
    }
  } else {
    const unsigned short* pB[NF];
#pragma unroll
    for (int f = 0; f < NF; ++f)
      pB[f] = (const unsigned short*)Bv + (size_t)(nrow0 + wave*(NF*16) + f*16 + l15)*ldb + k0 + lg*8;
    int k = k0;
    for (; k + 64 <= k1; k += 64){
      bf16x8 b0[NF], b1[NF], a0[4], a1[4];
#pragma unroll
      for (int f = 0; f < NF; ++f){
        b0[f] = *(const bf16x8*)(pB[f]);
        b1[f] = *(const bf16x8*)(pB[f]+32);
        pB[f] += 64;
      }
#pragma unroll
      for (int m = 0; m < 4; ++m){
        const unsigned short* p = pA + (size_t)m*16*lda;
        a0[m] = *(const bf16x8*)(p); a1[m] = *(const bf16x8*)(p+32);
      }
      pA += 64;
#pragma unroll
      for (int m = 0; m < 4; ++m)
#pragma unroll
        for (int f = 0; f < NF; ++f)
          acc[m][f] = __builtin_amdgcn_mfma_f32_16x16x32_bf16(a0[m], b0[f], acc[m][f], 0,0,0);
#pragma unroll
      for (int m = 0; m < 4; ++m)
#pragma unroll
        for (int f = 0; f < NF; ++f)
          acc[m][f] = __builtin_amdgcn_mfma_f32_16x16x32_bf16(a1[m], b1[f], acc[m][f], 0,0,0);
    }
    if (k < k1){
      bf16x8 b0[NF], a0[4];
#pragma unroll
      for (int f = 0; f < NF; ++f) b0[f] = *(const bf16x8*)(pB[f]);
#pragma unroll
      for (int m = 0; m < 4; ++m) a0[m] = *(const bf16x8*)(pA + (size_t)m*16*lda);
#pragma unroll
      for (int m = 0; m < 4; ++m)
#pragma unroll
        for (int f = 0; f < NF; ++f)
          acc[m][f] = __builtin_amdgcn_mfma_f32_16x16x32_bf16(a0[m], b0[f], acc[m][f], 0,0,0);
    }
  }
}

template<int NF>
__device__ __forceinline__ void store_out(f32x4 acc[4][NF], float* __restrict__ Out,
                                          int ldo, int col0){
  const int lane = threadIdx.x & 63;
  const int wave = threadIdx.x >> 6;
  const int l15 = lane & 15, lg = lane >> 4;
#pragma unroll
  for (int m = 0; m < 4; ++m)
#pragma unroll
    for (int f = 0; f < NF; ++f){
      int col = col0 + wave*(NF*16) + f*16 + l15;
#pragma unroll
      for (int j = 0; j < 4; ++j)
        Out[(size_t)(m*16 + lg*4 + j)*ldo + col] = acc[m][f][j];
    }
}

// ---- setup mega-kernel ----
#define E0 11110400u
#define E1 22220800u
#define E2 22860800u
#define E3 23500800u
#define E4 23520800u
#define E5 23540800u
#define E6 26305600u
#define E7 31220800u
#define E8 31417408u

__global__ __launch_bounds__(256) void k_setup(
    const float* __restrict__ Wihmu, const float* __restrict__ Wihlv,
    const float* __restrict__ Whhmu, const float* __restrict__ Whhlv,
    const float* __restrict__ Wmufc, const float* __restrict__ Wlvfc,
    const float* __restrict__ Whhdec, const float* __restrict__ Wihdec,
    const float* __restrict__ Wwrite, const float* __restrict__ x,
    unsigned short* __restrict__ wenc, unsigned short* __restrict__ whhmu,
    unsigned short* __restrict__ whhlv, unsigned short* __restrict__ wfcmu,
    unsigned short* __restrict__ wfclv, unsigned short* __restrict__ wdec,
    unsigned short* __restrict__ wwr, unsigned short* __restrict__ xbf)
{
  const float4* Wihmu4 = (const float4*)Wihmu;
  const float4* Wihlv4 = (const float4*)Wihlv;
  ushort4* wenc4 = (ushort4*)wenc;
  unsigned gstride = gridDim.x*blockDim.x;
  for (unsigned i0 = blockIdx.x*blockDim.x + threadIdx.x; i0 < E8; i0 += gstride){
    unsigned i = i0;
    if (i < E0){
      unsigned r = i/3472u, c = i - r*3472u;
      wenc4[(size_t)r*3472 + c] = cv4(Wihmu4[(size_t)r*6544 + 3072 + c]);
    } else if (i < E1){
      i -= E0; unsigned r = i/3472u, c = i - r*3472u;
      wenc4[(size_t)(r+3200)*3472 + c] = cv4(Wihlv4[(size_t)r*6544 + 3072 + c]);
    } else if (i < E2){ i -= E1; ((ushort4*)whhmu)[i] = cv4(((const float4*)Whhmu)[i]); }
    else if (i < E3){ i -= E2; ((ushort4*)whhlv)[i] = cv4(((const float4*)Whhlv)[i]); }
    else if (i < E4){ i -= E3; ((ushort4*)wfcmu)[i] = cv4(((const float4*)Wmufc)[i]); }
    else if (i < E5){ i -= E4; ((ushort4*)wfclv)[i] = cv4(((const float4*)Wlvfc)[i]); }
    else if (i < E6){
      i -= E5; unsigned pr = i/432u, c = i - pr*432u;
      unsigned j = pr >> 2, g = pr & 3, srow = g*1600u + j;
      float4 v = {0.f,0.f,0.f,0.f};
      if (c < 400u)      v = ((const float4*)Whhdec)[(size_t)srow*400 + c];
      else if (c < 425u) v = ((const float4*)Wihdec)[(size_t)srow*25 + (c-400u)];
      ((ushort4*)wdec)[(size_t)pr*432 + c] = cv4(v);
    }
    else if (i < E7){ i -= E6; ((ushort4*)wwr)[i] = cv4(((const float4*)Wwrite)[i]); }
    else { i -= E7; ((ushort4*)xbf)[i] = cv4(((const float4*)x)[i]); }
  }
}

// u sb-part = bf16(-sigmoid(0)) = bf16(-0.5) = 0xBF00
__global__ __launch_bounds__(256) void k_uinit(unsigned short* __restrict__ u){
  unsigned i = blockIdx.x*blockDim.x + threadIdx.x;     // 64*3072 ushort4 units
  if (i >= B_SZ*(KWB/4)) return;
  unsigned b = i / (KWB/4), c = i - b*(KWB/4);
  ushort4 v; v.x = 0xBF00u; v.y = 0xBF00u; v.z = 0xBF00u; v.w = 0xBF00u;
  *(ushort4*)(u + (size_t)b*KENC + c*4) = v;
}

// G0 = x@(W_A+W_B)^T, split-K 16: slices 0..7 read W_A from f32 inputs, 8..15 from wenc bf16
__global__ __launch_bounds__(256) void k_g0(const unsigned short* __restrict__ xbf,
                                            const float* __restrict__ Wihmu,
                                            const float* __restrict__ Wihlv,
                                            const unsigned short* __restrict__ wenc,
                                            float* __restrict__ gpart){
  int bid = blockIdx.x;            // 800 blocks: s = bid/50, cb = bid%50
  int s = bid/50, cb = bid - s*50;
  int col0 = cb*128;
  float* Out = gpart + (size_t)s*GSZ;
  f32x4 acc[4][2];
  if (s < 8){
    int k0 = s*1536;
    const float* Bf = (cb < 25) ? Wihmu : Wihlv;
    int nrow0 = (cb < 25) ? col0 : col0 - 3200;
    gemm_acc<2,1>(xbf, KWB, Bf, DENC, k0, k0+1536, nrow0, acc);
  } else {
    int k0 = (s-8)*1536;
    gemm_acc<2,0>(xbf, KWB, wenc, KENC, k0, k0+1536, col0, acc);
  }
  store_out<2>(acc, Out, NENC, col0);
}

__global__ __launch_bounds__(256) void k_g0red(const float* __restrict__ gpart,
                                               float* __restrict__ g0){
  unsigned i = blockIdx.x*blockDim.x + threadIdx.x;
  if (i >= GSZ) return;
  float s = 0.f;
#pragma unroll
  for (int p = 0; p < NSL; ++p) s += gpart[(size_t)p*GSZ + i];
  g0[i] = s;
}

// merged per-step enc GEMM (16 k-slices x 50 col-blocks) + hh GEMMs (100 blocks)
__global__ __launch_bounds__(256) void k_enc(const unsigned short* __restrict__ u,
                                             const unsigned short* __restrict__ wenc,
                                             const unsigned short* __restrict__ hmu,
                                             const unsigned short* __restrict__ hlv,
                                             const unsigned short* __restrict__ whhmu,
                                             const unsigned short* __restrict__ whhlv,
                                             float* __restrict__ gpart){
  int bid = blockIdx.x;
  if (bid < 800){
    int s = bid/50, cb = bid - s*50, col0 = cb*128;
    int k0 = s*832 + (s < 9 ? s : 9)*64;
    int k1 = k0 + (s < 9 ? 896 : 832);
    f32x4 acc[4][2];
    gemm_acc<2,0>(u, KENC, wenc, KENC, k0, k1, col0, acc);
    store_out<2>(acc, gpart + (size_t)s*GSZ, NENC, col0);
  } else {
    int nt = bid - 800;
    bool ismu = nt < 50;
    int c = ismu ? nt*64 : (nt-50)*64;
    f32x4 acc[4][1];
    gemm_acc<1,0>(ismu ? hmu : hlv, ENC_H, ismu ? whhmu : whhlv, ENC_H, 0, ENC_H, c, acc);
    store_out<1>(acc, gpart + (size_t)NSL*GSZ, NENC, ismu ? c : 3200 + c);
  }
}

// enc LSTM cell: 128 blocks = (b, which); reads g0 + 17 gpart slices
__global__ __launch_bounds__(256) void k_enc_cell(const float* __restrict__ g0,
                                                  const float* __restrict__ gpart,
                                                  const float* __restrict__ bmu,
                                                  const float* __restrict__ blv,
                                                  float* __restrict__ cmu,
                                                  float* __restrict__ clv,
                                                  unsigned short* __restrict__ hmu,
                                                  unsigned short* __restrict__ hlv){
  int b = blockIdx.x >> 1, w = blockIdx.x & 1;
  const float* bias = w ? blv : bmu;
  float* C = w ? clv : cmu;
  unsigned short* H = w ? hlv : hmu;
  int base = w * 3200;
  for (int j = threadIdx.x; j < ENC_H; j += 256){
    const float* q = g0 + (size_t)b*NENC + base + j;
    float gi = q[0], gf = q[ENC_H], gg = q[2*ENC_H], go = q[3*ENC_H];
#pragma unroll 1
    for (int s = 0; s < NSL+1; ++s){
      const float* p = gpart + (size_t)s*GSZ + (size_t)b*NENC + base + j;
      gi += p[0]; gf += p[ENC_H]; gg += p[2*ENC_H]; go += p[3*ENC_H];
    }
    gi += bias[j]; gf += bias[ENC_H+j]; gg += bias[2*ENC_H+j]; go += bias[3*ENC_H+j];
    float cold = C[(size_t)b*ENC_H + j];
    float cn = sigf(gf)*cold + sigf(gi)*tanhf(gg);
    float h  = sigf(go)*tanhf(cn);
    C[(size_t)b*ENC_H + j] = cn;
    H[(size_t)b*ENC_H + j] = f2bf(h);
  }
}

__global__ __launch_bounds__(256) void k_fc_z(const unsigned short* __restrict__ hmu,
                                              const unsigned short* __restrict__ hlv,
                                              const unsigned short* __restrict__ wfcmu,
                                              const unsigned short* __restrict__ wfclv,
                                              const float* __restrict__ bmufc,
                                              const float* __restrict__ blvfc,
                                              const float* __restrict__ noise_t,
                                              float* __restrict__ outMu,
                                              float* __restrict__ outLv,
                                              unsigned short* __restrict__ u2z){
  __shared__ float sm[2*NZ];
  int b = blockIdx.x, t = threadIdx.x;
  if (t < 2*NZ){
    bool ismu = t < NZ;
    int j = ismu ? t : t - NZ;
    const unsigned short* h = (ismu ? hmu : hlv) + (size_t)b*ENC_H;
    const unsigned short* wq = (ismu ? wfcmu : wfclv) + (size_t)j*ENC_H;
    const ushort4* h4 = (const ushort4*)h;
    const ushort4* w4 = (const ushort4*)wq;
    float s = 0.f;
#pragma unroll 4
    for (int k = 0; k < ENC_H/4; ++k){
      ushort4 hv = h4[k], wv = w4[k];
      s += bf2f(hv.x)*bf2f(wv.x) + bf2f(hv.y)*bf2f(wv.y)
         + bf2f(hv.z)*bf2f(wv.z) + bf2f(hv.w)*bf2f(wv.w);
    }
    s += ismu ? bmufc[j] : blvfc[j];
    s = fmaxf(s, 0.f);
    sm[t] = s;
    if (ismu) outMu[(size_t)b*NZ + j] = s;
    else      outLv[(size_t)b*NZ + j] = s;
  }
  __syncthreads();
  if (t < NZ){
    float mu = sm[t], lv = sm[NZ + t];
    float z = noise_t[(size_t)b*NZ + t]*__expf(0.5f*lv) + mu;
    u2z[(size_t)b*KDEC + DEC_H + t] = f2bf(z);
  }
}

// dec GEMM (gate-interleaved weights) fused with LSTM cell epilogue
__global__ __launch_bounds__(256) void k_dec(const unsigned short* __restrict__ u2r,
                                             const unsigned short* __restrict__ wdec,
                                             const float* __restrict__ bdec,
                                             float* __restrict__ cdec,
                                             unsigned short* __restrict__ u,
                                             unsigned short* __restrict__ u2w){
  __shared__ float lds[64*65];
  int bid = blockIdx.x;                       // 100 blocks, 16 hidden j each
  f32x4 acc[4][1];
  gemm_acc<1,0>(u2r, KDEC, wdec, KDEC, 0, KDEC, bid*64, acc);
  const int lane = threadIdx.x & 63;
  const int wave = threadIdx.x >> 6;
  const int l15 = lane & 15, lg = lane >> 4;
#pragma unroll
  for (int m = 0; m < 4; ++m)
#pragma unroll
    for (int j = 0; j < 4; ++j)
      lds[(m*16 + lg*4 + j)*65 + wave*16 + l15] = acc[m][0][j];
  __syncthreads();
#pragma unroll
  for (int p = 0; p < 4; ++p){
    int idx = threadIdx.x + p*256;
    int b = idx & 63, jj = idx >> 6;
    const float* g4 = &lds[b*65 + jj*4];
    int j = bid*16 + jj;
    float gi = g4[0] + bdec[j];
    float gf = g4[1] + bdec[DEC_H + j];
    float gg = g4[2] + bdec[2*DEC_H + j];
    float go = g4[3] + bdec[3*DEC_H + j];
    float cold = cdec[(size_t)b*DEC_H + j];
    float cn = sigf(gf)*cold + sigf(gi)*tanhf(gg);
    float h  = sigf(go)*tanhf(cn);
    cdec[(size_t)b*DEC_H + j] = cn;
    unsigned short hb = f2bf(h);
    u2w[(size_t)b*KDEC + j] = hb;             // next-step dec A / this-step write A
    u[(size_t)b*KENC + KWB + j] = hb;         // next-step enc h_dec slot
  }
}

// write GEMM fused: canvas += h_dec@Wwr^T + b ; u sb-part = bf16(-sigmoid(canvas))
__global__ __launch_bounds__(256) void k_write(const unsigned short* __restrict__ u2,
                                               const unsigned short* __restrict__ wwr,
                                               const float* __restrict__ bwr,
                                               float* __restrict__ canvas,
                                               unsigned short* __restrict__ u){
  f32x4 acc[4][1];
  gemm_acc<1,0>(u2, KDEC, wwr, DEC_H, 0, DEC_H, blockIdx.x*64, acc);
  const int lane = threadIdx.x & 63;
  const int wave = threadIdx.x >> 6;
  const int l15 = lane & 15, lg = lane >> 4;
#pragma unroll
  for (int m = 0; m < 4; ++m){
    int col = blockIdx.x*64 + wave*16 + l15;  // pixel index
#pragma unroll
    for (int j = 0; j < 4; ++j){
      int row = m*16 + lg*4 + j;              // batch
      float cv = canvas[(size_t)row*IMGSZ + col] + acc[m][0][j] + bwr[col];
      canvas[(size_t)row*IMGSZ + col] = cv;
      u[(size_t)row*KENC + col] = f2bf(-sigf(cv));
    }
  }
}

__global__ __launch_bounds__(256) void k_final(const float* __restrict__ canvas,
                                               float* __restrict__ out){
  unsigned i = blockIdx.x*blockDim.x + threadIdx.x;
  if (i < (unsigned)(B_SZ*IMGSZ)) out[i] = sigf(canvas[i]);
}

// ---- workspace layout ----
constexpr size_t SZ_WENC   = (size_t)NENC*KENC*2;      // 177,766,400
constexpr size_t SZ_WHH    = (size_t)3200*ENC_H*2;
constexpr size_t SZ_WFC    = (size_t)NZ*ENC_H*2;
constexpr size_t SZ_WDEC   = (size_t)NENC*KDEC*2;
constexpr size_t SZ_WWR    = (size_t)IMGSZ*DEC_H*2;
constexpr size_t SZ_XBF    = (size_t)B_SZ*KWB*2;
constexpr size_t SZ_G0     = (size_t)GSZ*4;
constexpr size_t SZ_GPART  = (size_t)(NSL+1)*GSZ*4;
constexpr size_t SZ_CANVAS = (size_t)B_SZ*IMGSZ*4;
constexpr size_t SZ_CMU    = (size_t)B_SZ*ENC_H*4;
constexpr size_t SZ_CDEC   = (size_t)B_SZ*DEC_H*4;
constexpr size_t SZ_HMU    = (size_t)B_SZ*ENC_H*2;
constexpr size_t SZ_U      = (size_t)B_SZ*KENC*2;
constexpr size_t SZ_U2     = (size_t)B_SZ*KDEC*2;

constexpr size_t OFF_WENC   = 0;
constexpr size_t OFF_WHHMU  = OFF_WENC   + SZ_WENC;
constexpr size_t OFF_WHHLV  = OFF_WHHMU  + SZ_WHH;
constexpr size_t OFF_WFCMU  = OFF_WHHLV  + SZ_WHH;
constexpr size_t OFF_WFCLV  = OFF_WFCMU  + SZ_WFC;
constexpr size_t OFF_WDEC   = OFF_WFCLV  + SZ_WFC;
constexpr size_t OFF_WWR    = OFF_WDEC   + SZ_WDEC;
constexpr size_t OFF_XBF    = OFF_WWR    + SZ_WWR;
constexpr size_t OFF_G0     = OFF_XBF    + SZ_XBF;
constexpr size_t OFF_GPART  = OFF_G0     + SZ_G0;
constexpr size_t OFF_CANVAS = OFF_GPART  + SZ_GPART;   // zero-init span starts here
constexpr size_t OFF_CMU    = OFF_CANVAS + SZ_CANVAS;
constexpr size_t OFF_CLV    = OFF_CMU    + SZ_CMU;
constexpr size_t OFF_CDEC   = OFF_CLV    + SZ_CMU;
constexpr size_t OFF_HMU    = OFF_CDEC   + SZ_CDEC;
constexpr size_t OFF_HLV    = OFF_HMU    + SZ_HMU;
constexpr size_t OFF_U      = OFF_HLV    + SZ_HMU;
constexpr size_t OFF_U2A    = OFF_U      + SZ_U;
constexpr size_t OFF_U2B    = OFF_U2A    + SZ_U2;
constexpr size_t OFF_END    = OFF_U2B    + SZ_U2;

extern "C" void kernel_launch(void* const* d_in, const int* in_sizes, int n_in,
                              void* d_out, int out_size, void* d_ws, size_t ws_size,
                              hipStream_t stream) {
  const float* x      = (const float*)d_in[0];
  const float* noise  = (const float*)d_in[1];
  const float* Wihmu  = (const float*)d_in[2];
  const float* Whhmu  = (const float*)d_in[3];
  const float* bmu    = (const float*)d_in[4];
  const float* Wihlv  = (const float*)d_in[5];
  const float* Whhlv  = (const float*)d_in[6];
  const float* blv    = (const float*)d_in[7];
  const float* Wmufc  = (const float*)d_in[8];
  const float* bmufc  = (const float*)d_in[9];
  const float* Wlvfc  = (const float*)d_in[10];
  const float* blvfc  = (const float*)d_in[11];
  const float* Wihdec = (const float*)d_in[12];
  const float* Whhdec = (const float*)d_in[13];
  const float* bdec   = (const float*)d_in[14];
  const float* Wwrite = (const float*)d_in[15];
  const float* bwrite = (const float*)d_in[16];
  int T = in_sizes[1] / (B_SZ*NZ);

  if (ws_size < OFF_END) return;

  char* ws = (char*)d_ws;
  unsigned short* wenc  = (unsigned short*)(ws + OFF_WENC);
  unsigned short* whhmu = (unsigned short*)(ws + OFF_WHHMU);
  unsigned short* whhlv = (unsigned short*)(ws + OFF_WHHLV);
  unsigned short* wfcmu = (unsigned short*)(ws + OFF_WFCMU);
  unsigned short* wfclv = (unsigned short*)(ws + OFF_WFCLV);
  unsigned short* wdec  = (unsigned short*)(ws + OFF_WDEC);
  unsigned short* wwr   = (unsigned short*)(ws + OFF_WWR);
  unsigned short* xbf   = (unsigned short*)(ws + OFF_XBF);
  float* g0     = (float*)(ws + OFF_G0);
  float* gpart  = (float*)(ws + OFF_GPART);
  float* canvas = (float*)(ws + OFF_CANVAS);
  float* cmu    = (float*)(ws + OFF_CMU);
  float* clv    = (float*)(ws + OFF_CLV);
  float* cdec   = (float*)(ws + OFF_CDEC);
  unsigned short* hmu = (unsigned short*)(ws + OFF_HMU);
  unsigned short* hlv = (unsigned short*)(ws + OFF_HLV);
  unsigned short* u   = (unsigned short*)(ws + OFF_U);
  unsigned short* u2[2] = { (unsigned short*)(ws + OFF_U2A),
                            (unsigned short*)(ws + OFF_U2B) };

  float* out = (float*)d_out;
  float* outMu = out + (size_t)B_SZ*IMGSZ;
  float* outLv = outMu + (size_t)T*B_SZ*NZ;

  dim3 blk(256);

  k_setup<<<4096, blk, 0, stream>>>(Wihmu, Wihlv, Whhmu, Whhlv, Wmufc, Wlvfc,
                                    Whhdec, Wihdec, Wwrite, x,
                                    wenc, whhmu, whhlv, wfcmu, wfclv, wdec, wwr, xbf);
  hipMemsetAsync(ws + OFF_CANVAS, 0, OFF_END - OFF_CANVAS, stream);
  k_uinit<<<(B_SZ*(KWB/4) + 255)/256, blk, 0, stream>>>(u);
  k_g0<<<800, blk, 0, stream>>>(xbf, Wihmu, Wihlv, wenc, gpart);
  k_g0red<<<GSZ/256, blk, 0, stream>>>(gpart, g0);

  for (int t = 0; t < T; ++t){
    unsigned short* u2r = u2[t & 1];
    unsigned short* u2w = u2[(t + 1) & 1];
    k_enc<<<900, blk, 0, stream>>>(u, wenc, hmu, hlv, whhmu, whhlv, gpart);
    k_enc_cell<<<2*B_SZ, blk, 0, stream>>>(g0, gpart, bmu, blv, cmu, clv, hmu, hlv);
    k_fc_z<<<B_SZ, blk, 0, stream>>>(hmu, hlv, wfcmu, wfclv, bmufc, blvfc,
                                     noise + (size_t)t*B_SZ*NZ,
                                     outMu + (size_t)t*B_SZ*NZ,
                                     outLv + (size_t)t*B_SZ*NZ, u2r);
    k_dec<<<100, blk, 0, stream>>>(u2r, wdec, bdec, cdec, u, u2w);
    k_write<<<IMGSZ/64, blk, 0, stream>>>(u2w, wwr, bwrite, canvas, u);
  }

  k_final<<<(B_SZ*IMGSZ)/256, blk, 0, stream>>>(canvas, out);
}

// Round 3
// 2403.210 us; speedup vs baseline: 1.0183x; 1.0183x over previous
//
#include <hip/hip_runtime.h>

typedef __attribute__((ext_vector_type(8))) short bf16x8;
typedef __attribute__((ext_vector_type(4))) float f32x4;

#define B_SZ   64
#define IMGSZ  12288            // 3*64*64
#define ENC_H  800
#define DEC_H  1600
#define NZ     100
#define NENC   6400             // 4*ENC_H*2 (mu ++ lv)
#define KENC   13888            // 12288 (sb) + 1600 (h_dec); 217 ksteps
#define KWB    12288            // 192 ksteps
#define KHH    832              // 800 padded; 13 ksteps
#define KDEC   1728             // 1600 + 100 + 28 pad; 27 ksteps
#define GSZ    (B_SZ*NENC)
#define NSL    16

__device__ __forceinline__ unsigned short f2bf(float f){
  unsigned u = __float_as_uint(f);
  u += 0x7fffu + ((u >> 16) & 1u);
  return (unsigned short)(u >> 16);
}
__device__ __forceinline__ float bf2f(unsigned short h){
  return __uint_as_float(((unsigned)h) << 16);
}
__device__ __forceinline__ float sigf(float x){ return 1.f/(1.f + __expf(-x)); }
__device__ __forceinline__ ushort4 cv4(float4 v){
  ushort4 o; o.x=f2bf(v.x); o.y=f2bf(v.y); o.z=f2bf(v.z); o.w=f2bf(v.w); return o;
}

// packed ushort4-index for tile layout [colblk][kstep][r in TC][kk in 64]
__device__ __forceinline__ size_t pk4(int col, int k4, int KK64, int TC){
  return ((size_t)(col/TC)*KK64 + (k4>>4))*((size_t)TC*16) + (size_t)(col%TC)*16 + (k4&15);
}

// ---- packed GEMM core: acc = A[64 x nks*64] * Bpk tile-slice ----
// Bpk packed as above; each wave-instruction reads a contiguous 1KB segment.
template<int NF>
__device__ __forceinline__ void gemm_pk(const unsigned short* __restrict__ A, int lda,
                                        const unsigned short* __restrict__ Bpk, int KK64,
                                        int colblk, int ks0, int nks,
                                        f32x4 acc[4][NF])
{
  const int lane = threadIdx.x & 63;
  const int wave = threadIdx.x >> 6;
  const int l15 = lane & 15, lg = lane >> 4;
  constexpr int TC = NF*64;

  const unsigned short* pA = A + (size_t)l15*lda + ks0*64 + lg*8;
  const unsigned short* pB = Bpk + ((size_t)colblk*KK64 + ks0)*((size_t)TC*64)
                             + (size_t)(wave*NF*16 + l15)*64 + lg*8;
#pragma unroll
  for (int m = 0; m < 4; ++m)
#pragma unroll
    for (int f = 0; f < NF; ++f)
      acc[m][f] = (f32x4){0.f,0.f,0.f,0.f};

  for (int ks = 0; ks < nks; ++ks){
    bf16x8 b0[NF], b1[NF], a0[4], a1[4];
#pragma unroll
    for (int f = 0; f < NF; ++f){
      b0[f] = *(const bf16x8*)(pB + f*1024);
      b1[f] = *(const bf16x8*)(pB + f*1024 + 32);
    }
#pragma unroll
    for (int m = 0; m < 4; ++m){
      const unsigned short* p = pA + (size_t)m*16*lda;
      a0[m] = *(const bf16x8*)(p); a1[m] = *(const bf16x8*)(p + 32);
    }
    pB += (size_t)TC*64; pA += 64;
#pragma unroll
    for (int m = 0; m < 4; ++m)
#pragma unroll
      for (int f = 0; f < NF; ++f)
        acc[m][f] = __builtin_amdgcn_mfma_f32_16x16x32_bf16(a0[m], b0[f], acc[m][f], 0,0,0);
#pragma unroll
    for (int m = 0; m < 4; ++m)
#pragma unroll
      for (int f = 0; f < NF; ++f)
        acc[m][f] = __builtin_amdgcn_mfma_f32_16x16x32_bf16(a1[m], b1[f], acc[m][f], 0,0,0);
  }
}

template<int NF>
__device__ __forceinline__ void store_out(f32x4 acc[4][NF], float* __restrict__ Out,
                                          int ldo, int col0){
  const int lane = threadIdx.x & 63;
  const int wave = threadIdx.x >> 6;
  const int l15 = lane & 15, lg = lane >> 4;
#pragma unroll
  for (int m = 0; m < 4; ++m)
#pragma unroll
    for (int f = 0; f < NF; ++f){
      int col = col0 + wave*(NF*16) + f*16 + l15;
#pragma unroll
      for (int j = 0; j < 4; ++j)
        Out[(size_t)(m*16 + lg*4 + j)*ldo + col] = acc[m][f][j];
    }
}

// ---- setup mega-kernel: convert + pack all weights ----
#define A_END 19660800u
#define B_END 22220800u
#define C_END 23552000u
#define D_END 26316800u
#define E_END 31232000u
#define F_END 31272000u
#define G_END 31468608u

__global__ __launch_bounds__(256) void k_setup(
    const float* __restrict__ Wihmu, const float* __restrict__ Wihlv,
    const float* __restrict__ Whhmu, const float* __restrict__ Whhlv,
    const float* __restrict__ Wmufc, const float* __restrict__ Wlvfc,
    const float* __restrict__ Whhdec, const float* __restrict__ Wihdec,
    const float* __restrict__ Wwrite, const float* __restrict__ x,
    unsigned short* __restrict__ wab, unsigned short* __restrict__ wenc,
    unsigned short* __restrict__ whh, unsigned short* __restrict__ wdec,
    unsigned short* __restrict__ wwr, unsigned short* __restrict__ wfcmu,
    unsigned short* __restrict__ wfclv, unsigned short* __restrict__ xbf)
{
  const float4* Wihmu4 = (const float4*)Wihmu;
  const float4* Wihlv4 = (const float4*)Wihlv;
  ushort4* wab4  = (ushort4*)wab;
  ushort4* wenc4 = (ushort4*)wenc;
  ushort4* whh4  = (ushort4*)whh;
  ushort4* wdec4 = (ushort4*)wdec;
  ushort4* wwr4  = (ushort4*)wwr;
  unsigned gstride = gridDim.x*blockDim.x;
  for (unsigned i0 = blockIdx.x*blockDim.x + threadIdx.x; i0 < G_END; i0 += gstride){
    unsigned i = i0;
    if (i < A_END){
      // enc cols, k<12288: wab = bf16(W_A+W_B), wenc = bf16(W_B)
      unsigned c = i/3072u, k4 = i - c*3072u;
      const float4* src = (c < 3200u) ? (Wihmu4 + (size_t)c*6544)
                                      : (Wihlv4 + (size_t)(c-3200u)*6544);
      float4 va = src[k4], vb = src[3072u + k4];
      float4 vs; vs.x=va.x+vb.x; vs.y=va.y+vb.y; vs.z=va.z+vb.z; vs.w=va.w+vb.w;
      wab4[pk4(c, k4, 192, 128)]  = cv4(vs);
      wenc4[pk4(c, k4, 217, 128)] = cv4(vb);
    } else if (i < B_END){
      // enc cols, k in [12288,13888): W_C region
      i -= A_END; unsigned c = i/400u, k4r = i - c*400u;
      const float4* src = (c < 3200u) ? (Wihmu4 + (size_t)c*6544)
                                      : (Wihlv4 + (size_t)(c-3200u)*6544);
      wenc4[pk4(c, 3072 + k4r, 217, 128)] = cv4(src[6144u + k4r]);
    } else if (i < C_END){
      // whh packed, K padded to 832; cols 0..3199 mu, 3200..6399 lv
      i -= B_END; unsigned c = i/208u, k4 = i - c*208u;
      float4 v = {0.f,0.f,0.f,0.f};
      if (k4 < 200u)
        v = (c < 3200u) ? ((const float4*)Whhmu)[(size_t)c*200 + k4]
                        : ((const float4*)Whhlv)[(size_t)(c-3200u)*200 + k4];
      whh4[pk4(c, k4, 13, 64)] = cv4(v);
    } else if (i < D_END){
      // wdec packed, gate-interleaved rows pr=j*4+g, K=1728 (pad from 1700)
      i -= C_END; unsigned pr = i/432u, k4 = i - pr*432u;
      unsigned j = pr >> 2, g = pr & 3, srow = g*1600u + j;
      float4 v = {0.f,0.f,0.f,0.f};
      if (k4 < 400u)      v = ((const float4*)Whhdec)[(size_t)srow*400 + k4];
      else if (k4 < 425u) v = ((const float4*)Wihdec)[(size_t)srow*25 + (k4-400u)];
      wdec4[pk4(pr, k4, 27, 64)] = cv4(v);
    } else if (i < E_END){
      i -= D_END; unsigned p = i/400u, k4 = i - p*400u;
      wwr4[pk4(p, k4, 25, 64)] = cv4(((const float4*)Wwrite)[(size_t)p*400 + k4]);
    } else if (i < F_END){
      i -= E_END;
      if (i < 20000u) ((ushort4*)wfcmu)[i] = cv4(((const float4*)Wmufc)[i]);
      else            ((ushort4*)wfclv)[i-20000u] = cv4(((const float4*)Wlvfc)[i-20000u]);
    } else {
      i -= F_END; ((ushort4*)xbf)[i] = cv4(((const float4*)x)[i]);
    }
  }
}

// u sb-part = bf16(-sigmoid(0)) = bf16(-0.5) = 0xBF00
__global__ __launch_bounds__(256) void k_uinit(unsigned short* __restrict__ u){
  unsigned i = blockIdx.x*blockDim.x + threadIdx.x;     // 64*3072 ushort4 units
  if (i >= B_SZ*(KWB/4)) return;
  unsigned b = i / (KWB/4), c = i - b*(KWB/4);
  ushort4 v; v.x = 0xBF00u; v.y = 0xBF00u; v.z = 0xBF00u; v.w = 0xBF00u;
  *(ushort4*)(u + (size_t)b*KENC + c*4) = v;
}

// G0 = x @ (W_A+W_B)^T from packed wab; 16 slices x 50 col-blocks
__global__ __launch_bounds__(256) void k_g0(const unsigned short* __restrict__ xbf,
                                            const unsigned short* __restrict__ wab,
                                            float* __restrict__ gpart){
  int bid = blockIdx.x;            // 800
  int s = bid/50, cb = bid - s*50;
  f32x4 acc[4][2];
  gemm_pk<2>(xbf, KWB, wab, 192, cb, s*12, 12, acc);
  store_out<2>(acc, gpart + (size_t)s*GSZ, NENC, cb*128);
}

__global__ __launch_bounds__(256) void k_g0red(const float* __restrict__ gpart,
                                               float* __restrict__ g0){
  unsigned i = blockIdx.x*blockDim.x + threadIdx.x;
  if (i >= GSZ) return;
  float s = 0.f;
#pragma unroll
  for (int p = 0; p < NSL; ++p) s += gpart[(size_t)p*GSZ + i];
  g0[i] = s;
}

// per-step enc GEMM (16 k-slices x 50 col-blocks) + hh GEMMs (100 blocks)
__global__ __launch_bounds__(256) void k_enc(const unsigned short* __restrict__ u,
                                             const unsigned short* __restrict__ wenc,
                                             const unsigned short* __restrict__ hmup,
                                             const unsigned short* __restrict__ hlvp,
                                             const unsigned short* __restrict__ whh,
                                             float* __restrict__ gpart){
  int bid = blockIdx.x;
  if (bid < 800){
    int s = bid/50, cb = bid - s*50;
    int ks0 = (s < 9) ? s*14 : 126 + (s-9)*13;
    int nks = (s < 9) ? 14 : 13;
    f32x4 acc[4][2];
    gemm_pk<2>(u, KENC, wenc, 217, cb, ks0, nks, acc);
    store_out<2>(acc, gpart + (size_t)s*GSZ, NENC, cb*128);
  } else {
    int nt = bid - 800;                      // 0..99: colblk over packed whh
    const unsigned short* A = (nt < 50) ? hmup : hlvp;
    f32x4 acc[4][1];
    gemm_pk<1>(A, KHH, whh, 13, nt, 0, 13, acc);
    store_out<1>(acc, gpart + (size_t)NSL*GSZ, NENC, nt*64);
  }
}

// enc LSTM cell: 128 blocks = (b, which); reads g0 + 17 gpart slices
__global__ __launch_bounds__(256) void k_enc_cell(const float* __restrict__ g0,
                                                  const float* __restrict__ gpart,
                                                  const float* __restrict__ bmu,
                                                  const float* __restrict__ blv,
                                                  float* __restrict__ cmu,
                                                  float* __restrict__ clv,
                                                  unsigned short* __restrict__ hmup,
                                                  unsigned short* __restrict__ hlvp){
  int b = blockIdx.x >> 1, w = blockIdx.x & 1;
  const float* bias = w ? blv : bmu;
  float* C = w ? clv : cmu;
  unsigned short* H = w ? hlvp : hmup;
  int base = w * 3200;
  for (int j = threadIdx.x; j < ENC_H; j += 256){
    const float* q = g0 + (size_t)b*NENC + base + j;
    float gi = q[0], gf = q[ENC_H], gg = q[2*ENC_H], go = q[3*ENC_H];
#pragma unroll 1
    for (int s = 0; s < NSL+1; ++s){
      const float* p = gpart + (size_t)s*GSZ + (size_t)b*NENC + base + j;
      gi += p[0]; gf += p[ENC_H]; gg += p[2*ENC_H]; go += p[3*ENC_H];
    }
    gi += bias[j]; gf += bias[ENC_H+j]; gg += bias[2*ENC_H+j]; go += bias[3*ENC_H+j];
    float cold = C[(size_t)b*ENC_H + j];
    float cn = sigf(gf)*cold + sigf(gi)*tanhf(gg);
    float h  = sigf(go)*tanhf(cn);
    C[(size_t)b*ENC_H + j] = cn;
    H[(size_t)b*KHH + j] = f2bf(h);
  }
}

__global__ __launch_bounds__(256) void k_fc_z(const unsigned short* __restrict__ hmup,
                                              const unsigned short* __restrict__ hlvp,
                                              const unsigned short* __restrict__ wfcmu,
                                              const unsigned short* __restrict__ wfclv,
                                              const float* __restrict__ bmufc,
                                              const float* __restrict__ blvfc,
                                              const float* __restrict__ noise_t,
                                              float* __restrict__ outMu,
                                              float* __restrict__ outLv,
                                              unsigned short* __restrict__ u2z){
  __shared__ float sm[2*NZ];
  int b = blockIdx.x, t = threadIdx.x;
  if (t < 2*NZ){
    bool ismu = t < NZ;
    int j = ismu ? t : t - NZ;
    const unsigned short* h = (ismu ? hmup : hlvp) + (size_t)b*KHH;
    const unsigned short* wq = (ismu ? wfcmu : wfclv) + (size_t)j*ENC_H;
    const ushort4* h4 = (const ushort4*)h;
    const ushort4* w4 = (const ushort4*)wq;
    float s = 0.f;
#pragma unroll 4
    for (int k = 0; k < ENC_H/4; ++k){
      ushort4 hv = h4[k], wv = w4[k];
      s += bf2f(hv.x)*bf2f(wv.x) + bf2f(hv.y)*bf2f(wv.y)
         + bf2f(hv.z)*bf2f(wv.z) + bf2f(hv.w)*bf2f(wv.w);
    }
    s += ismu ? bmufc[j] : blvfc[j];
    s = fmaxf(s, 0.f);
    sm[t] = s;
    if (ismu) outMu[(size_t)b*NZ + j] = s;
    else      outLv[(size_t)b*NZ + j] = s;
  }
  __syncthreads();
  if (t < NZ){
    float mu = sm[t], lv = sm[NZ + t];
    float z = noise_t[(size_t)b*NZ + t]*__expf(0.5f*lv) + mu;
    u2z[(size_t)b*KDEC + DEC_H + t] = f2bf(z);
  }
}

// dec GEMM (gate-interleaved packed weights) fused with LSTM cell epilogue
__global__ __launch_bounds__(256) void k_dec(const unsigned short* __restrict__ u2r,
                                             const unsigned short* __restrict__ wdec,
                                             const float* __restrict__ bdec,
                                             float* __restrict__ cdec,
                                             unsigned short* __restrict__ u,
                                             unsigned short* __restrict__ u2w){
  __shared__ float lds[64*65];
  int bid = blockIdx.x;                       // 100 blocks, 16 hidden j each
  f32x4 acc[4][1];
  gemm_pk<1>(u2r, KDEC, wdec, 27, bid, 0, 27, acc);
  const int lane = threadIdx.x & 63;
  const int wave = threadIdx.x >> 6;
  const int l15 = lane & 15, lg = lane >> 4;
#pragma unroll
  for (int m = 0; m < 4; ++m)
#pragma unroll
    for (int j = 0; j < 4; ++j)
      lds[(m*16 + lg*4 + j)*65 + wave*16 + l15] = acc[m][0][j];
  __syncthreads();
#pragma unroll
  for (int p = 0; p < 4; ++p){
    int idx = threadIdx.x + p*256;
    int b = idx & 63, jj = idx >> 6;
    const float* g4 = &lds[b*65 + jj*4];
    int j = bid*16 + jj;
    float gi = g4[0] + bdec[j];
    float gf = g4[1] + bdec[DEC_H + j];
    float gg = g4[2] + bdec[2*DEC_H + j];
    float go = g4[3] + bdec[3*DEC_H + j];
    float cold = cdec[(size_t)b*DEC_H + j];
    float cn = sigf(gf)*cold + sigf(gi)*tanhf(gg);
    float h  = sigf(go)*tanhf(cn);
    cdec[(size_t)b*DEC_H + j] = cn;
    unsigned short hb = f2bf(h);
    u2w[(size_t)b*KDEC + j] = hb;             // next-step dec A / this-step write A
    u[(size_t)b*KENC + KWB + j] = hb;         // next-step enc h_dec slot
  }
}

// write GEMM fused: canvas += h_dec@Wwr^T + b ; u sb-part = bf16(-sigmoid(canvas))
__global__ __launch_bounds__(256) void k_write(const unsigned short* __restrict__ u2,
                                               const unsigned short* __restrict__ wwr,
                                               const float* __restrict__ bwr,
                                               float* __restrict__ canvas,
                                               unsigned short* __restrict__ u){
  f32x4 acc[4][1];
  gemm_pk<1>(u2, KDEC, wwr, 25, blockIdx.x, 0, 25, acc);
  const int lane = threadIdx.x & 63;
  const int wave = threadIdx.x >> 6;
  const int l15 = lane & 15, lg = lane >> 4;
#pragma unroll
  for (int m = 0; m < 4; ++m){
    int col = blockIdx.x*64 + wave*16 + l15;  // pixel index
#pragma unroll
    for (int j = 0; j < 4; ++j){
      int row = m*16 + lg*4 + j;              // batch
      float cv = canvas[(size_t)row*IMGSZ + col] + acc[m][0][j] + bwr[col];
      canvas[(size_t)row*IMGSZ + col] = cv;
      u[(size_t)row*KENC + col] = f2bf(-sigf(cv));
    }
  }
}

__global__ __launch_bounds__(256) void k_final(const float* __restrict__ canvas,
                                               float* __restrict__ out){
  unsigned i = blockIdx.x*blockDim.x + threadIdx.x;
  if (i < (unsigned)(B_SZ*IMGSZ)) out[i] = sigf(canvas[i]);
}

// ---- workspace layout ----
constexpr size_t SZ_WAB    = (size_t)NENC*KWB*2;       // 157,286,400
constexpr size_t SZ_WENC   = (size_t)NENC*KENC*2;      // 177,766,400
constexpr size_t SZ_WHH    = (size_t)NENC*KHH*2;       // 10,649,600
constexpr size_t SZ_WDEC   = (size_t)NENC*KDEC*2;      // 22,118,400
constexpr size_t SZ_WWR    = (size_t)IMGSZ*DEC_H*2;    // 39,321,600
constexpr size_t SZ_WFC    = (size_t)NZ*ENC_H*2;
constexpr size_t SZ_XBF    = (size_t)B_SZ*KWB*2;
constexpr size_t SZ_G0     = (size_t)GSZ*4;
constexpr size_t SZ_GPART  = (size_t)(NSL+1)*GSZ*4;
constexpr size_t SZ_CANVAS = (size_t)B_SZ*IMGSZ*4;
constexpr size_t SZ_CMU    = (size_t)B_SZ*ENC_H*4;
constexpr size_t SZ_CDEC   = (size_t)B_SZ*DEC_H*4;
constexpr size_t SZ_HP     = (size_t)B_SZ*KHH*2;
constexpr size_t SZ_U      = (size_t)B_SZ*KENC*2;
constexpr size_t SZ_U2     = (size_t)B_SZ*KDEC*2;

constexpr size_t OFF_WAB    = 0;
constexpr size_t OFF_WENC   = OFF_WAB    + SZ_WAB;
constexpr size_t OFF_WHH    = OFF_WENC   + SZ_WENC;
constexpr size_t OFF_WDEC   = OFF_WHH    + SZ_WHH;
constexpr size_t OFF_WWR    = OFF_WDEC   + SZ_WDEC;
constexpr size_t OFF_WFCMU  = OFF_WWR    + SZ_WWR;
constexpr size_t OFF_WFCLV  = OFF_WFCMU  + SZ_WFC;
constexpr size_t OFF_XBF    = OFF_WFCLV  + SZ_WFC;
constexpr size_t OFF_G0     = OFF_XBF    + SZ_XBF;
constexpr size_t OFF_GPART  = OFF_G0     + SZ_G0;
constexpr size_t OFF_CANVAS = OFF_GPART  + SZ_GPART;   // zero-init span starts here
constexpr size_t OFF_CMU    = OFF_CANVAS + SZ_CANVAS;
constexpr size_t OFF_CLV    = OFF_CMU    + SZ_CMU;
constexpr size_t OFF_CDEC   = OFF_CLV    + SZ_CMU;
constexpr size_t OFF_HMUP   = OFF_CDEC   + SZ_CDEC;
constexpr size_t OFF_HLVP   = OFF_HMUP   + SZ_HP;
constexpr size_t OFF_U      = OFF_HLVP   + SZ_HP;
constexpr size_t OFF_U2A    = OFF_U      + SZ_U;
constexpr size_t OFF_U2B    = OFF_U2A    + SZ_U2;
constexpr size_t OFF_END    = OFF_U2B    + SZ_U2;

extern "C" void kernel_launch(void* const* d_in, const int* in_sizes, int n_in,
                              void* d_out, int out_size, void* d_ws, size_t ws_size,
                              hipStream_t stream) {
  const float* x      = (const float*)d_in[0];
  const float* noise  = (const float*)d_in[1];
  const float* Wihmu  = (const float*)d_in[2];
  const float* Whhmu  = (const float*)d_in[3];
  const float* bmu    = (const float*)d_in[4];
  const float* Wihlv  = (const float*)d_in[5];
  const float* Whhlv  = (const float*)d_in[6];
  const float* blv    = (const float*)d_in[7];
  const float* Wmufc  = (const float*)d_in[8];
  const float* bmufc  = (const float*)d_in[9];
  const float* Wlvfc  = (const float*)d_in[10];
  const float* blvfc  = (const float*)d_in[11];
  const float* Wihdec = (const float*)d_in[12];
  const float* Whhdec = (const float*)d_in[13];
  const float* bdec   = (const float*)d_in[14];
  const float* Wwrite = (const float*)d_in[15];
  const float* bwrite = (const float*)d_in[16];
  int T = in_sizes[1] / (B_SZ*NZ);

  if (ws_size < OFF_END) return;

  char* ws = (char*)d_ws;
  unsigned short* wab   = (unsigned short*)(ws + OFF_WAB);
  unsigned short* wenc  = (unsigned short*)(ws + OFF_WENC);
  unsigned short* whh   = (unsigned short*)(ws + OFF_WHH);
  unsigned short* wdec  = (unsigned short*)(ws + OFF_WDEC);
  unsigned short* wwr   = (unsigned short*)(ws + OFF_WWR);
  unsigned short* wfcmu = (unsigned short*)(ws + OFF_WFCMU);
  unsigned short* wfclv = (unsigned short*)(ws + OFF_WFCLV);
  unsigned short* xbf   = (unsigned short*)(ws + OFF_XBF);
  float* g0     = (float*)(ws + OFF_G0);
  float* gpart  = (float*)(ws + OFF_GPART);
  float* canvas = (float*)(ws + OFF_CANVAS);
  float* cmu    = (float*)(ws + OFF_CMU);
  float* clv    = (float*)(ws + OFF_CLV);
  float* cdec   = (float*)(ws + OFF_CDEC);
  unsigned short* hmup = (unsigned short*)(ws + OFF_HMUP);
  unsigned short* hlvp = (unsigned short*)(ws + OFF_HLVP);
  unsigned short* u    = (unsigned short*)(ws + OFF_U);
  unsigned short* u2[2] = { (unsigned short*)(ws + OFF_U2A),
                            (unsigned short*)(ws + OFF_U2B) };

  float* out = (float*)d_out;
  float* outMu = out + (size_t)B_SZ*IMGSZ;
  float* outLv = outMu + (size_t)T*B_SZ*NZ;

  dim3 blk(256);

  k_setup<<<4096, blk, 0, stream>>>(Wihmu, Wihlv, Whhmu, Whhlv, Wmufc, Wlvfc,
                                    Whhdec, Wihdec, Wwrite, x,
                                    wab, wenc, whh, wdec, wwr, wfcmu, wfclv, xbf);
  hipMemsetAsync(ws + OFF_CANVAS, 0, OFF_END - OFF_CANVAS, stream);
  k_uinit<<<(B_SZ*(KWB/4) + 255)/256, blk, 0, stream>>>(u);
  k_g0<<<800, blk, 0, stream>>>(xbf, wab, gpart);
  k_g0red<<<GSZ/256, blk, 0, stream>>>(gpart, g0);

  for (int t = 0; t < T; ++t){
    unsigned short* u2r = u2[t & 1];
    unsigned short* u2w = u2[(t + 1) & 1];
    k_enc<<<900, blk, 0, stream>>>(u, wenc, hmup, hlvp, whh, gpart);
    k_enc_cell<<<2*B_SZ, blk, 0, stream>>>(g0, gpart, bmu, blv, cmu, clv, hmup, hlvp);
    k_fc_z<<<B_SZ, blk, 0, stream>>>(hmup, hlvp, wfcmu, wfclv, bmufc, blvfc,
                                     noise + (size_t)t*B_SZ*NZ,
                                     outMu + (size_t)t*B_SZ*NZ,
                                     outLv + (size_t)t*B_SZ*NZ, u2r);
    k_dec<<<100, blk, 0, stream>>>(u2r, wdec, bdec, cdec, u, u2w);
    k_write<<<IMGSZ/64, blk, 0, stream>>>(u2w, wwr, bwrite, canvas, u);
  }

  k_final<<<(B_SZ*IMGSZ)/256, blk, 0, stream>>>(canvas, out);
}

// Round 4
// 1614.293 us; speedup vs baseline: 1.5160x; 1.4887x over previous
//
#include <hip/hip_runtime.h>

typedef __attribute__((ext_vector_type(8))) short bf16x8;
typedef __attribute__((ext_vector_type(4))) float f32x4;
typedef unsigned int u32;

#define B_SZ   64
#define IMGSZ  12288            // 3*64*64
#define ENC_H  800
#define DEC_H  1600
#define NZ     100
#define NENC   6400             // 4*ENC_H*2 (mu ++ lv)
#define KENC   13888            // 217 chunks of 64
#define KHH    832              // 13 chunks
#define KDEC   1728             // 27 chunks
#define GSZ    (B_SZ*NENC)
#define NSL    16               // enc k-slices; slice 16 = hh
#define G0SL   8

__device__ __forceinline__ unsigned short f2bf(float f){
  unsigned u = __float_as_uint(f);
  u += 0x7fffu + ((u >> 16) & 1u);
  return (unsigned short)(u >> 16);
}
__device__ __forceinline__ float bf2f(unsigned short h){
  return __uint_as_float(((unsigned)h) << 16);
}
__device__ __forceinline__ float sigf(float x){ return 1.f/(1.f + __expf(-x)); }
__device__ __forceinline__ ushort4 cv4(float4 v){
  ushort4 o; o.x=f2bf(v.x); o.y=f2bf(v.y); o.z=f2bf(v.z); o.w=f2bf(v.w); return o;
}

// packed ushort4-index: 64-col blocks, 64-k chunks, XOR-swizzled units.
// (col,k): r=col&63, ch=k/64, u=(k%64)/8 stored at su=u^(r&7); e=k%8.
__device__ __forceinline__ size_t pknew(unsigned col, unsigned k4, unsigned nch){
  unsigned blk = col>>6, r = col&63, ch = k4>>4, uu = (k4>>1)&7, half = k4&1;
  unsigned su = uu ^ (r&7);
  return ((size_t)(blk*nch + ch)*64 + r)*16 + su*2 + half;
}

__device__ __forceinline__ void gll16(const unsigned short* g, unsigned short* l){
  __builtin_amdgcn_global_load_lds((const __attribute__((address_space(1))) u32*)g,
                                   (__attribute__((address_space(3))) u32*)l, 16, 0, 0);
}

// ---- LDS-staged GEMM core: acc = A[64 x nchb*64] * Bpk-slice^T ----
// Block=256thr; wave w -> output cols colblk*64 + w*16 + l15.
// smem[4][4096]: buf b -> A=sm[2b], B=sm[2b+1]. One barrier per 64-k chunk.
__device__ __forceinline__ void gemm_lds(const unsigned short* __restrict__ A, int lda, int k0,
                                         const unsigned short* __restrict__ Bpk, size_t bchunk0,
                                         int nchb, unsigned short (*sm)[4096], f32x4 acc[4])
{
  const int tid = threadIdx.x;
  const int lane = tid & 63, w = tid >> 6;
  const int l15 = lane & 15, lg = lane >> 4;
  const int l8 = lane >> 3, l7 = lane & 7;

  // A gather: issue j covers rows w*16+j*8..+8; logical u = l7^l8 realizes the
  // XOR tile layout through the linear LDS deposit (per-lane global source).
  const unsigned short* gA0 = A + (size_t)(w*16 + l8)*lda + k0 + (l7 ^ l8)*8;
  const unsigned short* gA1 = gA0 + (size_t)8*lda;
  const unsigned short* gB0 = Bpk + bchunk0*4096 + w*1024 + lane*8;

#pragma unroll
  for (int m = 0; m < 4; ++m) acc[m] = (f32x4){0.f,0.f,0.f,0.f};

  gll16(gA0, &sm[0][(w*2+0)*512]);
  gll16(gA1, &sm[0][(w*2+1)*512]);
  gll16(gB0,       &sm[1][w*1024]);
  gll16(gB0 + 512, &sm[1][w*1024 + 512]);
  __syncthreads();

  for (int c = 0; c < nchb; ++c){
    const int cur = c & 1;
    if (c + 1 < nchb){
      const size_t ao = (size_t)(c+1)*64;
      const size_t bo = (size_t)(c+1)*4096;
      unsigned short* nA = sm[(cur^1)*2];
      unsigned short* nB = sm[(cur^1)*2 + 1];
      gll16(gA0 + ao, nA + (w*2+0)*512);
      gll16(gA1 + ao, nA + (w*2+1)*512);
      gll16(gB0 + bo,       nB + w*1024);
      gll16(gB0 + bo + 512, nB + w*1024 + 512);
    }
    const unsigned short* sa = sm[cur*2];
    const unsigned short* sb = sm[cur*2 + 1];
#pragma unroll
    for (int h = 0; h < 2; ++h){
      const int su8 = (((h*4 + lg) ^ (l15 & 7))) * 8;
      bf16x8 bfr = *(const bf16x8*)&sb[(w*16 + l15)*64 + su8];
#pragma unroll
      for (int m = 0; m < 4; ++m){
        bf16x8 afr = *(const bf16x8*)&sa[(m*16 + l15)*64 + su8];
        acc[m] = __builtin_amdgcn_mfma_f32_16x16x32_bf16(afr, bfr, acc[m], 0,0,0);
      }
    }
    __syncthreads();
  }
}

__device__ __forceinline__ void store_out1(f32x4 acc[4], float* __restrict__ Out,
                                           int ldo, int col0){
  const int lane = threadIdx.x & 63, w = threadIdx.x >> 6;
  const int l15 = lane & 15, lg = lane >> 4;
  int col = col0 + w*16 + l15;
#pragma unroll
  for (int m = 0; m < 4; ++m)
#pragma unroll
    for (int j = 0; j < 4; ++j)
      Out[(size_t)(m*16 + lg*4 + j)*ldo + col] = acc[m][j];
}

// ---- setup mega-kernel: convert + pack all weights (XOR-swizzled tiles) ----
#define A_END 19660800u
#define B_END 22220800u
#define C_END 23552000u
#define D_END 26316800u
#define E_END 31232000u
#define F_END 31272000u
#define G_END 31468608u

__global__ __launch_bounds__(256) void k_setup(
    const float* __restrict__ Wihmu, const float* __restrict__ Wihlv,
    const float* __restrict__ Whhmu, const float* __restrict__ Whhlv,
    const float* __restrict__ Wmufc, const float* __restrict__ Wlvfc,
    const float* __restrict__ Whhdec, const float* __restrict__ Wihdec,
    const float* __restrict__ Wwrite, const float* __restrict__ x,
    unsigned short* __restrict__ wab, unsigned short* __restrict__ wenc,
    unsigned short* __restrict__ whh, unsigned short* __restrict__ wdec,
    unsigned short* __restrict__ wwr, unsigned short* __restrict__ wfcmu,
    unsigned short* __restrict__ wfclv, unsigned short* __restrict__ xbf)
{
  const float4* Wihmu4 = (const float4*)Wihmu;
  const float4* Wihlv4 = (const float4*)Wihlv;
  ushort4* wab4  = (ushort4*)wab;
  ushort4* wenc4 = (ushort4*)wenc;
  ushort4* whh4  = (ushort4*)whh;
  ushort4* wdec4 = (ushort4*)wdec;
  ushort4* wwr4  = (ushort4*)wwr;
  unsigned gstride = gridDim.x*blockDim.x;
  for (unsigned i0 = blockIdx.x*blockDim.x + threadIdx.x; i0 < G_END; i0 += gstride){
    unsigned i = i0;
    if (i < A_END){
      unsigned c = i/3072u, k4 = i - c*3072u;
      const float4* src = (c < 3200u) ? (Wihmu4 + (size_t)c*6544)
                                      : (Wihlv4 + (size_t)(c-3200u)*6544);
      float4 va = src[k4], vb = src[3072u + k4];
      float4 vs; vs.x=va.x+vb.x; vs.y=va.y+vb.y; vs.z=va.z+vb.z; vs.w=va.w+vb.w;
      wab4[pknew(c, k4, 192)]  = cv4(vs);
      wenc4[pknew(c, k4, 217)] = cv4(vb);
    } else if (i < B_END){
      i -= A_END; unsigned c = i/400u, k4r = i - c*400u;
      const float4* src = (c < 3200u) ? (Wihmu4 + (size_t)c*6544)
                                      : (Wihlv4 + (size_t)(c-3200u)*6544);
      wenc4[pknew(c, 3072u + k4r, 217)] = cv4(src[6144u + k4r]);
    } else if (i < C_END){
      i -= B_END; unsigned c = i/208u, k4 = i - c*208u;
      float4 v = {0.f,0.f,0.f,0.f};
      if (k4 < 200u)
        v = (c < 3200u) ? ((const float4*)Whhmu)[(size_t)c*200 + k4]
                        : ((const float4*)Whhlv)[(size_t)(c-3200u)*200 + k4];
      whh4[pknew(c, k4, 13)] = cv4(v);
    } else if (i < D_END){
      i -= C_END; unsigned pr = i/432u, k4 = i - pr*432u;
      unsigned j = pr >> 2, g = pr & 3, srow = g*1600u + j;
      float4 v = {0.f,0.f,0.f,0.f};
      if (k4 < 400u)      v = ((const float4*)Whhdec)[(size_t)srow*400 + k4];
      else if (k4 < 425u) v = ((const float4*)Wihdec)[(size_t)srow*25 + (k4-400u)];
      wdec4[pknew(pr, k4, 27)] = cv4(v);
    } else if (i < E_END){
      i -= D_END; unsigned p = i/400u, k4 = i - p*400u;
      wwr4[pknew(p, k4, 25)] = cv4(((const float4*)Wwrite)[(size_t)p*400 + k4]);
    } else if (i < F_END){
      i -= E_END;
      if (i < 20000u) ((ushort4*)wfcmu)[i] = cv4(((const float4*)Wmufc)[i]);
      else            ((ushort4*)wfclv)[i-20000u] = cv4(((const float4*)Wlvfc)[i-20000u]);
    } else {
      i -= F_END; ((ushort4*)xbf)[i] = cv4(((const float4*)x)[i]);
    }
  }
}

__global__ __launch_bounds__(256) void k_uinit(unsigned short* __restrict__ u){
  unsigned i = blockIdx.x*blockDim.x + threadIdx.x;
  if (i >= B_SZ*(IMGSZ/4)) return;
  unsigned b = i / (IMGSZ/4), c = i - b*(IMGSZ/4);
  ushort4 v; v.x = 0xBF00u; v.y = 0xBF00u; v.z = 0xBF00u; v.w = 0xBF00u;
  *(ushort4*)(u + (size_t)b*KENC + c*4) = v;
}

__global__ __launch_bounds__(256) void k_g0(const unsigned short* __restrict__ xbf,
                                            const unsigned short* __restrict__ wab,
                                            float* __restrict__ gpart){
  __shared__ __align__(16) unsigned short smem[4][4096];
  int bid = blockIdx.x;                 // 800
  int s = bid/100, cb = bid - s*100;
  f32x4 acc[4];
  gemm_lds(xbf, IMGSZ, s*1536, wab, (size_t)cb*192 + s*24, 24, smem, acc);
  store_out1(acc, gpart + (size_t)s*GSZ, NENC, cb*64);
}

__global__ __launch_bounds__(256) void k_g0red(const float* __restrict__ gpart,
                                               float* __restrict__ g0){
  unsigned i = blockIdx.x*blockDim.x + threadIdx.x;
  if (i >= GSZ) return;
  float s = 0.f;
#pragma unroll
  for (int p = 0; p < G0SL; ++p) s += gpart[(size_t)p*GSZ + i];
  g0[i] = s;
}

__global__ __launch_bounds__(256) void k_enc(const unsigned short* __restrict__ u,
                                             const unsigned short* __restrict__ wenc,
                                             const unsigned short* __restrict__ hmup,
                                             const unsigned short* __restrict__ hlvp,
                                             const unsigned short* __restrict__ whh,
                                             float* __restrict__ gpart){
  __shared__ __align__(16) unsigned short smem[4][4096];
  int bid = blockIdx.x;
  f32x4 acc[4];
  if (bid < 1600){
    int s = bid/100, cb = bid - s*100;
    int ch0 = (s < 9) ? s*14 : 126 + (s-9)*13;
    int nchb = (s < 9) ? 14 : 13;
    gemm_lds(u, KENC, ch0*64, wenc, (size_t)cb*217 + ch0, nchb, smem, acc);
    store_out1(acc, gpart + (size_t)s*GSZ, NENC, cb*64);
  } else {
    int cb = bid - 1600;                 // 0..99
    const unsigned short* A = (cb < 50) ? hmup : hlvp;
    gemm_lds(A, KHH, 0, whh, (size_t)cb*13, 13, smem, acc);
    store_out1(acc, gpart + (size_t)NSL*GSZ, NENC, cb*64);
  }
}

__global__ __launch_bounds__(256) void k_enc_cell(const float* __restrict__ g0,
                                                  const float* __restrict__ gpart,
                                                  const float* __restrict__ bmu,
                                                  const float* __restrict__ blv,
                                                  float* __restrict__ cmu,
                                                  float* __restrict__ clv,
                                                  unsigned short* __restrict__ hmup,
                                                  unsigned short* __restrict__ hlvp){
  int b = blockIdx.x >> 1, w = blockIdx.x & 1;
  const float* bias = w ? blv : bmu;
  float* C = w ? clv : cmu;
  unsigned short* H = w ? hlvp : hmup;
  int base = w * 3200;
  for (int j = threadIdx.x; j < ENC_H; j += 256){
    const float* q = g0 + (size_t)b*NENC + base + j;
    float gi = q[0], gf = q[ENC_H], gg = q[2*ENC_H], go = q[3*ENC_H];
#pragma unroll 1
    for (int s = 0; s < NSL+1; ++s){
      const float* p = gpart + (size_t)s*GSZ + (size_t)b*NENC + base + j;
      gi += p[0]; gf += p[ENC_H]; gg += p[2*ENC_H]; go += p[3*ENC_H];
    }
    gi += bias[j]; gf += bias[ENC_H+j]; gg += bias[2*ENC_H+j]; go += bias[3*ENC_H+j];
    float cold = C[(size_t)b*ENC_H + j];
    float cn = sigf(gf)*cold + sigf(gi)*tanhf(gg);
    float h  = sigf(go)*tanhf(cn);
    C[(size_t)b*ENC_H + j] = cn;
    H[(size_t)b*KHH + j] = f2bf(h);
  }
}

__global__ __launch_bounds__(256) void k_fc_z(const unsigned short* __restrict__ hmup,
                                              const unsigned short* __restrict__ hlvp,
                                              const unsigned short* __restrict__ wfcmu,
                                              const unsigned short* __restrict__ wfclv,
                                              const float* __restrict__ bmufc,
                                              const float* __restrict__ blvfc,
                                              const float* __restrict__ noise_t,
                                              float* __restrict__ outMu,
                                              float* __restrict__ outLv,
                                              unsigned short* __restrict__ u2z){
  __shared__ float sm[2*NZ];
  int b = blockIdx.x, t = threadIdx.x;
  if (t < 2*NZ){
    bool ismu = t < NZ;
    int j = ismu ? t : t - NZ;
    const unsigned short* h = (ismu ? hmup : hlvp) + (size_t)b*KHH;
    const unsigned short* wq = (ismu ? wfcmu : wfclv) + (size_t)j*ENC_H;
    const ushort4* h4 = (const ushort4*)h;
    const ushort4* w4 = (const ushort4*)wq;
    float s = 0.f;
#pragma unroll 4
    for (int k = 0; k < ENC_H/4; ++k){
      ushort4 hv = h4[k], wv = w4[k];
      s += bf2f(hv.x)*bf2f(wv.x) + bf2f(hv.y)*bf2f(wv.y)
         + bf2f(hv.z)*bf2f(wv.z) + bf2f(hv.w)*bf2f(wv.w);
    }
    s += ismu ? bmufc[j] : blvfc[j];
    s = fmaxf(s, 0.f);
    sm[t] = s;
    if (ismu) outMu[(size_t)b*NZ + j] = s;
    else      outLv[(size_t)b*NZ + j] = s;
  }
  __syncthreads();
  if (t < NZ){
    float mu = sm[t], lv = sm[NZ + t];
    float z = noise_t[(size_t)b*NZ + t]*__expf(0.5f*lv) + mu;
    u2z[(size_t)b*KDEC + DEC_H + t] = f2bf(z);
  }
}

__global__ __launch_bounds__(256) void k_dec(const unsigned short* __restrict__ u2r,
                                             const unsigned short* __restrict__ wdec,
                                             const float* __restrict__ bdec,
                                             float* __restrict__ cdec,
                                             unsigned short* __restrict__ u,
                                             unsigned short* __restrict__ u2w){
  __shared__ __align__(16) unsigned short smem[4][4096];
  int bid = blockIdx.x;                       // 100 blocks, 16 hidden j each
  f32x4 acc[4];
  gemm_lds(u2r, KDEC, 0, wdec, (size_t)bid*27, 27, smem, acc);
  float* lds = (float*)&smem[0][0];           // 64x65 f32 = 16.6KB < 32KB
  const int lane = threadIdx.x & 63;
  const int wave = threadIdx.x >> 6;
  const int l15 = lane & 15, lg = lane >> 4;
#pragma unroll
  for (int m = 0; m < 4; ++m)
#pragma unroll
    for (int j = 0; j < 4; ++j)
      lds[(m*16 + lg*4 + j)*65 + wave*16 + l15] = acc[m][j];
  __syncthreads();
#pragma unroll
  for (int p = 0; p < 4; ++p){
    int idx = threadIdx.x + p*256;
    int b = idx & 63, jj = idx >> 6;
    const float* g4 = &lds[b*65 + jj*4];
    int j = bid*16 + jj;
    float gi = g4[0] + bdec[j];
    float gf = g4[1] + bdec[DEC_H + j];
    float gg = g4[2] + bdec[2*DEC_H + j];
    float go = g4[3] + bdec[3*DEC_H + j];
    float cold = cdec[(size_t)b*DEC_H + j];
    float cn = sigf(gf)*cold + sigf(gi)*tanhf(gg);
    float h  = sigf(go)*tanhf(cn);
    cdec[(size_t)b*DEC_H + j] = cn;
    unsigned short hb = f2bf(h);
    u2w[(size_t)b*KDEC + j] = hb;
    u[(size_t)b*KENC + IMGSZ + j] = hb;
  }
}

__global__ __launch_bounds__(256) void k_write(const unsigned short* __restrict__ u2,
                                               const unsigned short* __restrict__ wwr,
                                               const float* __restrict__ bwr,
                                               float* __restrict__ canvas,
                                               unsigned short* __restrict__ u){
  __shared__ __align__(16) unsigned short smem[4][4096];
  f32x4 acc[4];
  gemm_lds(u2, KDEC, 0, wwr, (size_t)blockIdx.x*25, 25, smem, acc);
  const int lane = threadIdx.x & 63;
  const int wave = threadIdx.x >> 6;
  const int l15 = lane & 15, lg = lane >> 4;
  int col = blockIdx.x*64 + wave*16 + l15;
#pragma unroll
  for (int m = 0; m < 4; ++m){
#pragma unroll
    for (int j = 0; j < 4; ++j){
      int row = m*16 + lg*4 + j;
      float cv = canvas[(size_t)row*IMGSZ + col] + acc[m][j] + bwr[col];
      canvas[(size_t)row*IMGSZ + col] = cv;
      u[(size_t)row*KENC + col] = f2bf(-sigf(cv));
    }
  }
}

__global__ __launch_bounds__(256) void k_final(const float* __restrict__ canvas,
                                               float* __restrict__ out){
  unsigned i = blockIdx.x*blockDim.x + threadIdx.x;
  if (i < (unsigned)(B_SZ*IMGSZ)) out[i] = sigf(canvas[i]);
}

// ---- workspace layout ----
constexpr size_t SZ_WAB    = (size_t)NENC*IMGSZ*2;
constexpr size_t SZ_WENC   = (size_t)NENC*KENC*2;
constexpr size_t SZ_WHH    = (size_t)NENC*KHH*2;
constexpr size_t SZ_WDEC   = (size_t)NENC*KDEC*2;
constexpr size_t SZ_WWR    = (size_t)IMGSZ*DEC_H*2;
constexpr size_t SZ_WFC    = (size_t)NZ*ENC_H*2;
constexpr size_t SZ_XBF    = (size_t)B_SZ*IMGSZ*2;
constexpr size_t SZ_G0     = (size_t)GSZ*4;
constexpr size_t SZ_GPART  = (size_t)(NSL+1)*GSZ*4;
constexpr size_t SZ_CANVAS = (size_t)B_SZ*IMGSZ*4;
constexpr size_t SZ_CMU    = (size_t)B_SZ*ENC_H*4;
constexpr size_t SZ_CDEC   = (size_t)B_SZ*DEC_H*4;
constexpr size_t SZ_HP     = (size_t)B_SZ*KHH*2;
constexpr size_t SZ_U      = (size_t)B_SZ*KENC*2;
constexpr size_t SZ_U2     = (size_t)B_SZ*KDEC*2;

constexpr size_t OFF_WAB    = 0;
constexpr size_t OFF_WENC   = OFF_WAB    + SZ_WAB;
constexpr size_t OFF_WHH    = OFF_WENC   + SZ_WENC;
constexpr size_t OFF_WDEC   = OFF_WHH    + SZ_WHH;
constexpr size_t OFF_WWR    = OFF_WDEC   + SZ_WDEC;
constexpr size_t OFF_WFCMU  = OFF_WWR    + SZ_WWR;
constexpr size_t OFF_WFCLV  = OFF_WFCMU  + SZ_WFC;
constexpr size_t OFF_XBF    = OFF_WFCLV  + SZ_WFC;
constexpr size_t OFF_G0     = OFF_XBF    + SZ_XBF;
constexpr size_t OFF_GPART  = OFF_G0     + SZ_G0;
constexpr size_t OFF_CANVAS = OFF_GPART  + SZ_GPART;
constexpr size_t OFF_CMU    = OFF_CANVAS + SZ_CANVAS;
constexpr size_t OFF_CLV    = OFF_CMU    + SZ_CMU;
constexpr size_t OFF_CDEC   = OFF_CLV    + SZ_CMU;
constexpr size_t OFF_HMUP   = OFF_CDEC   + SZ_CDEC;
constexpr size_t OFF_HLVP   = OFF_HMUP   + SZ_HP;
constexpr size_t OFF_U      = OFF_HLVP   + SZ_HP;
constexpr size_t OFF_U2A    = OFF_U      + SZ_U;
constexpr size_t OFF_U2B    = OFF_U2A    + SZ_U2;
constexpr size_t OFF_END    = OFF_U2B    + SZ_U2;

extern "C" void kernel_launch(void* const* d_in, const int* in_sizes, int n_in,
                              void* d_out, int out_size, void* d_ws, size_t ws_size,
                              hipStream_t stream) {
  const float* x      = (const float*)d_in[0];
  const float* noise  = (const float*)d_in[1];
  const float* Wihmu  = (const float*)d_in[2];
  const float* Whhmu  = (const float*)d_in[3];
  const float* bmu    = (const float*)d_in[4];
  const float* Wihlv  = (const float*)d_in[5];
  const float* Whhlv  = (const float*)d_in[6];
  const float* blv    = (const float*)d_in[7];
  const float* Wmufc  = (const float*)d_in[8];
  const float* bmufc  = (const float*)d_in[9];
  const float* Wlvfc  = (const float*)d_in[10];
  const float* blvfc  = (const float*)d_in[11];
  const float* Wihdec = (const float*)d_in[12];
  const float* Whhdec = (const float*)d_in[13];
  const float* bdec   = (const float*)d_in[14];
  const float* Wwrite = (const float*)d_in[15];
  const float* bwrite = (const float*)d_in[16];
  int T = in_sizes[1] / (B_SZ*NZ);

  if (ws_size < OFF_END) return;

  char* ws = (char*)d_ws;
  unsigned short* wab   = (unsigned short*)(ws + OFF_WAB);
  unsigned short* wenc  = (unsigned short*)(ws + OFF_WENC);
  unsigned short* whh   = (unsigned short*)(ws + OFF_WHH);
  unsigned short* wdec  = (unsigned short*)(ws + OFF_WDEC);
  unsigned short* wwr   = (unsigned short*)(ws + OFF_WWR);
  unsigned short* wfcmu = (unsigned short*)(ws + OFF_WFCMU);
  unsigned short* wfclv = (unsigned short*)(ws + OFF_WFCLV);
  unsigned short* xbf   = (unsigned short*)(ws + OFF_XBF);
  float* g0     = (float*)(ws + OFF_G0);
  float* gpart  = (float*)(ws + OFF_GPART);
  float* canvas = (float*)(ws + OFF_CANVAS);
  float* cmu    = (float*)(ws + OFF_CMU);
  float* clv    = (float*)(ws + OFF_CLV);
  float* cdec   = (float*)(ws + OFF_CDEC);
  unsigned short* hmup = (unsigned short*)(ws + OFF_HMUP);
  unsigned short* hlvp = (unsigned short*)(ws + OFF_HLVP);
  unsigned short* u    = (unsigned short*)(ws + OFF_U);
  unsigned short* u2[2] = { (unsigned short*)(ws + OFF_U2A),
                            (unsigned short*)(ws + OFF_U2B) };

  float* out = (float*)d_out;
  float* outMu = out + (size_t)B_SZ*IMGSZ;
  float* outLv = outMu + (size_t)T*B_SZ*NZ;

  dim3 blk(256);

  k_setup<<<4096, blk, 0, stream>>>(Wihmu, Wihlv, Whhmu, Whhlv, Wmufc, Wlvfc,
                                    Whhdec, Wihdec, Wwrite, x,
                                    wab, wenc, whh, wdec, wwr, wfcmu, wfclv, xbf);
  hipMemsetAsync(ws + OFF_CANVAS, 0, OFF_END - OFF_CANVAS, stream);
  k_uinit<<<(B_SZ*(IMGSZ/4) + 255)/256, blk, 0, stream>>>(u);
  k_g0<<<800, blk, 0, stream>>>(xbf, wab, gpart);
  k_g0red<<<GSZ/256, blk, 0, stream>>>(gpart, g0);

  for (int t = 0; t < T; ++t){
    unsigned short* u2r = u2[t & 1];
    unsigned short* u2w = u2[(t + 1) & 1];
    k_enc<<<1700, blk, 0, stream>>>(u, wenc, hmup, hlvp, whh, gpart);
    k_enc_cell<<<2*B_SZ, blk, 0, stream>>>(g0, gpart, bmu, blv, cmu, clv, hmup, hlvp);
    k_fc_z<<<B_SZ, blk, 0, stream>>>(hmup, hlvp, wfcmu, wfclv, bmufc, blvfc,
                                     noise + (size_t)t*B_SZ*NZ,
                                     outMu + (size_t)t*B_SZ*NZ,
                                     outLv + (size_t)t*B_SZ*NZ, u2r);
    k_dec<<<100, blk, 0, stream>>>(u2r, wdec, bdec, cdec, u, u2w);
    k_write<<<IMGSZ/64, blk, 0, stream>>>(u2w, wwr, bwrite, canvas, u);
  }

  k_final<<<(B_SZ*IMGSZ)/256, blk, 0, stream>>>(canvas, out);
}

// Round 5
// 1410.386 us; speedup vs baseline: 1.7352x; 1.1446x over previous
//
#include <hip/hip_runtime.h>

typedef __attribute__((ext_vector_type(8))) short bf16x8;
typedef __attribute__((ext_vector_type(4))) float f32x4;
typedef unsigned int u32;

#define B_SZ   64
#define IMGSZ  12288            // 3*64*64
#define ENC_H  800
#define DEC_H  1600
#define NZ     100
#define NENC   6400             // 4*ENC_H*2 (mu ++ lv)
#define KENC   13888            // 217 chunks of 64
#define KHH    832              // 13 chunks
#define KDEC   1728             // 27 chunks
#define GSZ    (B_SZ*NENC)
#define NSL    16               // enc k-slices; slice 16 = hh
#define G0SL   8

__device__ __forceinline__ unsigned short f2bf(float f){
  unsigned u = __float_as_uint(f);
  u += 0x7fffu + ((u >> 16) & 1u);
  return (unsigned short)(u >> 16);
}
__device__ __forceinline__ float bf2f(unsigned short h){
  return __uint_as_float(((unsigned)h) << 16);
}
__device__ __forceinline__ float sigf(float x){ return 1.f/(1.f + __expf(-x)); }
__device__ __forceinline__ ushort4 cv4(float4 v){
  ushort4 o; o.x=f2bf(v.x); o.y=f2bf(v.y); o.z=f2bf(v.z); o.w=f2bf(v.w); return o;
}

// packed ushort4-index: 64-col blocks, 64-k chunks, XOR-swizzled units.
// (col,k): r=col&63, ch=k/64, u=(k%64)/8 stored at su=u^(r&7); e=k%8.
__device__ __forceinline__ size_t pknew(unsigned col, unsigned k4, unsigned nch){
  unsigned blk = col>>6, r = col&63, ch = k4>>4, uu = (k4>>1)&7, half = k4&1;
  unsigned su = uu ^ (r&7);
  return ((size_t)(blk*nch + ch)*64 + r)*16 + su*2 + half;
}

__device__ __forceinline__ void gll16(const unsigned short* g, unsigned short* l){
  __builtin_amdgcn_global_load_lds((const __attribute__((address_space(1))) u32*)g,
                                   (__attribute__((address_space(3))) u32*)l, 16, 0, 0);
}

// ---- LDS-staged GEMM, 3-buffer pipeline with counted vmcnt ----
// Block=256thr; wave w -> output cols colblk*64 + w*16 + l15.
// smem[6][4096]: buf b -> A=sm[2b], B=sm[2b+1]. One raw barrier per chunk;
// loads stay in flight across barriers (vmcnt(4) steady state, never 0).
__device__ __forceinline__ void gemm_lds3(const unsigned short* __restrict__ A, int lda, int k0,
                                          const unsigned short* __restrict__ Bpk, size_t bchunk0,
                                          int nchb, unsigned short (*sm)[4096], f32x4 acc[4])
{
  const int tid = threadIdx.x;
  const int lane = tid & 63, w = tid >> 6;
  const int l15 = lane & 15, lg = lane >> 4;
  const int l8 = lane >> 3, l7 = lane & 7;

  // A gather: logical u = l7^l8 realizes the XOR tile layout through the
  // linear LDS deposit (per-lane global source address, m173 pattern).
  const unsigned short* gA0 = A + (size_t)(w*16 + l8)*lda + k0 + (l7 ^ l8)*8;
  const unsigned short* gA1 = gA0 + (size_t)8*lda;
  const unsigned short* gB0 = Bpk + bchunk0*4096 + w*1024 + lane*8;

#pragma unroll
  for (int m = 0; m < 4; ++m) acc[m] = (f32x4){0.f,0.f,0.f,0.f};

  // prologue: chunk 0 -> buf0, chunk 1 -> buf1
  gll16(gA0, &sm[0][(w*2+0)*512]);
  gll16(gA1, &sm[0][(w*2+1)*512]);
  gll16(gB0,       &sm[1][w*1024]);
  gll16(gB0 + 512, &sm[1][w*1024 + 512]);
  if (1 < nchb){
    gll16(gA0 + 64, &sm[2][(w*2+0)*512]);
    gll16(gA1 + 64, &sm[2][(w*2+1)*512]);
    gll16(gB0 + 4096,       &sm[3][w*1024]);
    gll16(gB0 + 4096 + 512, &sm[3][w*1024 + 512]);
  }

  int cur = 0, nxt = 2;
  for (int c = 0; c < nchb; ++c){
    if (c + 1 < nchb) { asm volatile("s_waitcnt vmcnt(4)" ::: "memory"); }
    else              { asm volatile("s_waitcnt vmcnt(0)" ::: "memory"); }
    asm volatile("s_barrier" ::: "memory");
    const unsigned short* sa = sm[cur*2];
    const unsigned short* sb = sm[cur*2 + 1];
#pragma unroll
    for (int h = 0; h < 2; ++h){
      const int su8 = ((h*4 + lg) ^ (l15 & 7)) * 8;
      bf16x8 bfr = *(const bf16x8*)&sb[(w*16 + l15)*64 + su8];
#pragma unroll
      for (int m = 0; m < 4; ++m){
        bf16x8 afr = *(const bf16x8*)&sa[(m*16 + l15)*64 + su8];
        acc[m] = __builtin_amdgcn_mfma_f32_16x16x32_bf16(afr, bfr, acc[m], 0,0,0);
      }
    }
    if (c + 2 < nchb){
      const size_t ao = (size_t)(c+2)*64, bo = (size_t)(c+2)*4096;
      gll16(gA0 + ao, &sm[nxt*2][(w*2+0)*512]);
      gll16(gA1 + ao, &sm[nxt*2][(w*2+1)*512]);
      gll16(gB0 + bo,       &sm[nxt*2+1][w*1024]);
      gll16(gB0 + bo + 512, &sm[nxt*2+1][w*1024 + 512]);
    }
    cur = (cur==2) ? 0 : cur+1;
    nxt = (nxt==2) ? 0 : nxt+1;
  }
}

__device__ __forceinline__ void store_out1(f32x4 acc[4], float* __restrict__ Out,
                                           int ldo, int col0){
  const int lane = threadIdx.x & 63, w = threadIdx.x >> 6;
  const int l15 = lane & 15, lg = lane >> 4;
  int col = col0 + w*16 + l15;
#pragma unroll
  for (int m = 0; m < 4; ++m)
#pragma unroll
    for (int j = 0; j < 4; ++j)
      Out[(size_t)(m*16 + lg*4 + j)*ldo + col] = acc[m][j];
}

// ---- setup mega-kernel: convert + pack all weights (XOR-swizzled tiles) ----
#define A_END 19660800u
#define B_END 22220800u
#define C_END 23552000u
#define D_END 26316800u
#define E_END 31232000u
#define F_END 31272000u
#define G_END 31468608u

__global__ __launch_bounds__(256) void k_setup(
    const float* __restrict__ Wihmu, const float* __restrict__ Wihlv,
    const float* __restrict__ Whhmu, const float* __restrict__ Whhlv,
    const float* __restrict__ Wmufc, const float* __restrict__ Wlvfc,
    const float* __restrict__ Whhdec, const float* __restrict__ Wihdec,
    const float* __restrict__ Wwrite, const float* __restrict__ x,
    unsigned short* __restrict__ wab, unsigned short* __restrict__ wenc,
    unsigned short* __restrict__ whh, unsigned short* __restrict__ wdec,
    unsigned short* __restrict__ wwr, unsigned short* __restrict__ wfcmu,
    unsigned short* __restrict__ wfclv, unsigned short* __restrict__ xbf)
{
  const float4* Wihmu4 = (const float4*)Wihmu;
  const float4* Wihlv4 = (const float4*)Wihlv;
  ushort4* wab4  = (ushort4*)wab;
  ushort4* wenc4 = (ushort4*)wenc;
  ushort4* whh4  = (ushort4*)whh;
  ushort4* wdec4 = (ushort4*)wdec;
  ushort4* wwr4  = (ushort4*)wwr;
  unsigned gstride = gridDim.x*blockDim.x;
  for (unsigned i0 = blockIdx.x*blockDim.x + threadIdx.x; i0 < G_END; i0 += gstride){
    unsigned i = i0;
    if (i < A_END){
      unsigned c = i/3072u, k4 = i - c*3072u;
      const float4* src = (c < 3200u) ? (Wihmu4 + (size_t)c*6544)
                                      : (Wihlv4 + (size_t)(c-3200u)*6544);
      float4 va = src[k4], vb = src[3072u + k4];
      float4 vs; vs.x=va.x+vb.x; vs.y=va.y+vb.y; vs.z=va.z+vb.z; vs.w=va.w+vb.w;
      wab4[pknew(c, k4, 192)]  = cv4(vs);
      wenc4[pknew(c, k4, 217)] = cv4(vb);
    } else if (i < B_END){
      i -= A_END; unsigned c = i/400u, k4r = i - c*400u;
      const float4* src = (c < 3200u) ? (Wihmu4 + (size_t)c*6544)
                                      : (Wihlv4 + (size_t)(c-3200u)*6544);
      wenc4[pknew(c, 3072u + k4r, 217)] = cv4(src[6144u + k4r]);
    } else if (i < C_END){
      i -= B_END; unsigned c = i/208u, k4 = i - c*208u;
      float4 v = {0.f,0.f,0.f,0.f};
      if (k4 < 200u)
        v = (c < 3200u) ? ((const float4*)Whhmu)[(size_t)c*200 + k4]
                        : ((const float4*)Whhlv)[(size_t)(c-3200u)*200 + k4];
      whh4[pknew(c, k4, 13)] = cv4(v);
    } else if (i < D_END){
      i -= C_END; unsigned pr = i/432u, k4 = i - pr*432u;
      unsigned j = pr >> 2, g = pr & 3, srow = g*1600u + j;
      float4 v = {0.f,0.f,0.f,0.f};
      if (k4 < 400u)      v = ((const float4*)Whhdec)[(size_t)srow*400 + k4];
      else if (k4 < 425u) v = ((const float4*)Wihdec)[(size_t)srow*25 + (k4-400u)];
      wdec4[pknew(pr, k4, 27)] = cv4(v);
    } else if (i < E_END){
      i -= D_END; unsigned p = i/400u, k4 = i - p*400u;
      wwr4[pknew(p, k4, 25)] = cv4(((const float4*)Wwrite)[(size_t)p*400 + k4]);
    } else if (i < F_END){
      i -= E_END;
      if (i < 20000u) ((ushort4*)wfcmu)[i] = cv4(((const float4*)Wmufc)[i]);
      else            ((ushort4*)wfclv)[i-20000u] = cv4(((const float4*)Wlvfc)[i-20000u]);
    } else {
      i -= F_END; ((ushort4*)xbf)[i] = cv4(((const float4*)x)[i]);
    }
  }
}

__global__ __launch_bounds__(256) void k_uinit(unsigned short* __restrict__ u){
  unsigned i = blockIdx.x*blockDim.x + threadIdx.x;
  if (i >= B_SZ*(IMGSZ/4)) return;
  unsigned b = i / (IMGSZ/4), c = i - b*(IMGSZ/4);
  ushort4 v; v.x = 0xBF00u; v.y = 0xBF00u; v.z = 0xBF00u; v.w = 0xBF00u;
  *(ushort4*)(u + (size_t)b*KENC + c*4) = v;
}

__global__ __launch_bounds__(256) void k_g0(const unsigned short* __restrict__ xbf,
                                            const unsigned short* __restrict__ wab,
                                            float* __restrict__ gpart){
  __shared__ __align__(16) unsigned short smem[6][4096];
  int bid = blockIdx.x;                 // 800
  int s = bid/100, cb = bid - s*100;
  f32x4 acc[4];
  gemm_lds3(xbf, IMGSZ, s*1536, wab, (size_t)cb*192 + s*24, 24, smem, acc);
  store_out1(acc, gpart + (size_t)s*GSZ, NENC, cb*64);
}

__global__ __launch_bounds__(256) void k_g0red(const float* __restrict__ gpart,
                                               float* __restrict__ g0){
  unsigned i = blockIdx.x*blockDim.x + threadIdx.x;
  if (i >= GSZ) return;
  float s = 0.f;
#pragma unroll
  for (int p = 0; p < G0SL; ++p) s += gpart[(size_t)p*GSZ + i];
  g0[i] = s;
}

__global__ __launch_bounds__(256) void k_enc(const unsigned short* __restrict__ u,
                                             const unsigned short* __restrict__ wenc,
                                             const unsigned short* __restrict__ hmup,
                                             const unsigned short* __restrict__ hlvp,
                                             const unsigned short* __restrict__ whh,
                                             float* __restrict__ gpart){
  __shared__ __align__(16) unsigned short smem[6][4096];
  int bid = blockIdx.x;
  f32x4 acc[4];
  if (bid < 1600){
    int s = bid/100, cb = bid - s*100;
    int ch0 = (s < 9) ? s*14 : 126 + (s-9)*13;
    int nchb = (s < 9) ? 14 : 13;
    gemm_lds3(u, KENC, ch0*64, wenc, (size_t)cb*217 + ch0, nchb, smem, acc);
    store_out1(acc, gpart + (size_t)s*GSZ, NENC, cb*64);
  } else {
    int cb = bid - 1600;                 // 0..99
    const unsigned short* A = (cb < 50) ? hmup : hlvp;
    gemm_lds3(A, KHH, 0, whh, (size_t)cb*13, 13, smem, acc);
    store_out1(acc, gpart + (size_t)NSL*GSZ, NENC, cb*64);
  }
}

// merged enc LSTM cell + mu/lv fc + z: 64 blocks (one per batch), 512 thr
__global__ __launch_bounds__(512) void k_cell(const float* __restrict__ g0,
                                              const float* __restrict__ gpart,
                                              const float* __restrict__ bmu,
                                              const float* __restrict__ blv,
                                              float* __restrict__ cmu,
                                              float* __restrict__ clv,
                                              unsigned short* __restrict__ hmup,
                                              unsigned short* __restrict__ hlvp,
                                              const unsigned short* __restrict__ wfcmu,
                                              const unsigned short* __restrict__ wfclv,
                                              const float* __restrict__ bmufc,
                                              const float* __restrict__ blvfc,
                                              const float* __restrict__ noise_t,
                                              float* __restrict__ outMu,
                                              float* __restrict__ outLv,
                                              unsigned short* __restrict__ u2z){
  __shared__ float hsh[1600];
  __shared__ float red[512];
  int b = blockIdx.x, tid = threadIdx.x;

  for (int uidx = tid; uidx < 1600; uidx += 512){
    int which = uidx >= 800;
    int j = uidx - which*800;
    const float* bias = which ? blv : bmu;
    size_t rowoff = (size_t)b*NENC + which*3200 + j;
    float a0 = bias[j], a1 = bias[800+j], a2 = bias[1600+j], a3 = bias[2400+j];
    const float* q = g0 + rowoff;
    a0 += q[0]; a1 += q[800]; a2 += q[1600]; a3 += q[2400];
#pragma unroll
    for (int s = 0; s < NSL+1; ++s){
      const float* p = gpart + (size_t)s*GSZ + rowoff;
      a0 += p[0]; a1 += p[800]; a2 += p[1600]; a3 += p[2400];
    }
    float* C = which ? clv : cmu;
    float cold = C[(size_t)b*ENC_H + j];
    float cn = sigf(a1)*cold + sigf(a0)*tanhf(a2);
    float h  = sigf(a3)*tanhf(cn);
    C[(size_t)b*ENC_H + j] = cn;
    (which ? hlvp : hmup)[(size_t)b*KHH + j] = f2bf(h);
    hsh[uidx] = h;
  }
  __syncthreads();

  if (tid < 400){                         // 200 outputs x 2 K-halves
    int o = tid >> 1, half = tid & 1;
    int ismu = o < 100;
    int row = ismu ? o : o - 100;
    const unsigned short* wrow = (ismu ? wfcmu : wfclv) + (size_t)row*ENC_H + half*400;
    const float* hbase = hsh + (ismu ? 0 : 800) + half*400;
    float s = 0.f;
#pragma unroll 4
    for (int k = 0; k < 100; ++k){
      ushort4 wv = ((const ushort4*)wrow)[k];
      s += bf2f(wv.x)*hbase[k*4]   + bf2f(wv.y)*hbase[k*4+1]
         + bf2f(wv.z)*hbase[k*4+2] + bf2f(wv.w)*hbase[k*4+3];
    }
    red[tid] = s;
  }
  __syncthreads();
  if (tid < 200){
    int o = tid; int ismu = o < 100; int row = ismu ? o : o - 100;
    float s = red[2*o] + red[2*o+1] + (ismu ? bmufc[row] : blvfc[row]);
    s = fmaxf(s, 0.f);
    if (ismu) outMu[(size_t)b*NZ + row] = s;
    else      outLv[(size_t)b*NZ + row] = s;
    hsh[o] = s;                           // stash mu(0..99), lv(100..199)
  }
  __syncthreads();
  if (tid < 100){
    float mu = hsh[tid], lv = hsh[100 + tid];
    float z = noise_t[(size_t)b*NZ + tid]*__expf(0.5f*lv) + mu;
    u2z[(size_t)b*KDEC + DEC_H + tid] = f2bf(z);
  }
}

__global__ __launch_bounds__(256) void k_dec(const unsigned short* __restrict__ u2r,
                                             const unsigned short* __restrict__ wdec,
                                             const float* __restrict__ bdec,
                                             float* __restrict__ cdec,
                                             unsigned short* __restrict__ u,
                                             unsigned short* __restrict__ u2w){
  __shared__ __align__(16) unsigned short smem[6][4096];
  int bid = blockIdx.x;                       // 100 blocks, 16 hidden j each
  f32x4 acc[4];
  gemm_lds3(u2r, KDEC, 0, wdec, (size_t)bid*27, 27, smem, acc);
  __syncthreads();
  float* lds = (float*)&smem[0][0];           // 64x65 f32 = 16.6KB < 48KB
  const int lane = threadIdx.x & 63;
  const int wave = threadIdx.x >> 6;
  const int l15 = lane & 15, lg = lane >> 4;
#pragma unroll
  for (int m = 0; m < 4; ++m)
#pragma unroll
    for (int j = 0; j < 4; ++j)
      lds[(m*16 + lg*4 + j)*65 + wave*16 + l15] = acc[m][j];
  __syncthreads();
#pragma unroll
  for (int p = 0; p < 4; ++p){
    int idx = threadIdx.x + p*256;
    int b = idx & 63, jj = idx >> 6;
    const float* g4 = &lds[b*65 + jj*4];
    int j = bid*16 + jj;
    float gi = g4[0] + bdec[j];
    float gf = g4[1] + bdec[DEC_H + j];
    float gg = g4[2] + bdec[2*DEC_H + j];
    float go = g4[3] + bdec[3*DEC_H + j];
    float cold = cdec[(size_t)b*DEC_H + j];
    float cn = sigf(gf)*cold + sigf(gi)*tanhf(gg);
    float h  = sigf(go)*tanhf(cn);
    cdec[(size_t)b*DEC_H + j] = cn;
    unsigned short hb = f2bf(h);
    u2w[(size_t)b*KDEC + j] = hb;
    u[(size_t)b*KENC + IMGSZ + j] = hb;
  }
}

__global__ __launch_bounds__(256) void k_write(const unsigned short* __restrict__ u2,
                                               const unsigned short* __restrict__ wwr,
                                               const float* __restrict__ bwr,
                                               float* __restrict__ canvas,
                                               unsigned short* __restrict__ u){
  __shared__ __align__(16) unsigned short smem[6][4096];
  f32x4 acc[4];
  gemm_lds3(u2, KDEC, 0, wwr, (size_t)blockIdx.x*25, 25, smem, acc);
  const int lane = threadIdx.x & 63;
  const int wave = threadIdx.x >> 6;
  const int l15 = lane & 15, lg = lane >> 4;
  int col = blockIdx.x*64 + wave*16 + l15;
#pragma unroll
  for (int m = 0; m < 4; ++m){
#pragma unroll
    for (int j = 0; j < 4; ++j){
      int row = m*16 + lg*4 + j;
      float cv = canvas[(size_t)row*IMGSZ + col] + acc[m][j] + bwr[col];
      canvas[(size_t)row*IMGSZ + col] = cv;
      u[(size_t)row*KENC + col] = f2bf(-sigf(cv));
    }
  }
}

__global__ __launch_bounds__(256) void k_final(const float* __restrict__ canvas,
                                               float* __restrict__ out){
  unsigned i = blockIdx.x*blockDim.x + threadIdx.x;
  if (i < (unsigned)(B_SZ*IMGSZ)) out[i] = sigf(canvas[i]);
}

// ---- workspace layout ----
constexpr size_t SZ_WAB    = (size_t)NENC*IMGSZ*2;
constexpr size_t SZ_WENC   = (size_t)NENC*KENC*2;
constexpr size_t SZ_WHH    = (size_t)NENC*KHH*2;
constexpr size_t SZ_WDEC   = (size_t)NENC*KDEC*2;
constexpr size_t SZ_WWR    = (size_t)IMGSZ*DEC_H*2;
constexpr size_t SZ_WFC    = (size_t)NZ*ENC_H*2;
constexpr size_t SZ_XBF    = (size_t)B_SZ*IMGSZ*2;
constexpr size_t SZ_G0     = (size_t)GSZ*4;
constexpr size_t SZ_GPART  = (size_t)(NSL+1)*GSZ*4;
constexpr size_t SZ_CANVAS = (size_t)B_SZ*IMGSZ*4;
constexpr size_t SZ_CMU    = (size_t)B_SZ*ENC_H*4;
constexpr size_t SZ_CDEC   = (size_t)B_SZ*DEC_H*4;
constexpr size_t SZ_HP     = (size_t)B_SZ*KHH*2;
constexpr size_t SZ_U      = (size_t)B_SZ*KENC*2;
constexpr size_t SZ_U2     = (size_t)B_SZ*KDEC*2;

constexpr size_t OFF_WAB    = 0;
constexpr size_t OFF_WENC   = OFF_WAB    + SZ_WAB;
constexpr size_t OFF_WHH    = OFF_WENC   + SZ_WENC;
constexpr size_t OFF_WDEC   = OFF_WHH    + SZ_WHH;
constexpr size_t OFF_WWR    = OFF_WDEC   + SZ_WDEC;
constexpr size_t OFF_WFCMU  = OFF_WWR    + SZ_WWR;
constexpr size_t OFF_WFCLV  = OFF_WFCMU  + SZ_WFC;
constexpr size_t OFF_XBF    = OFF_WFCLV  + SZ_WFC;
constexpr size_t OFF_G0     = OFF_XBF    + SZ_XBF;
constexpr size_t OFF_GPART  = OFF_G0     + SZ_G0;
constexpr size_t OFF_CANVAS = OFF_GPART  + SZ_GPART;
constexpr size_t OFF_CMU    = OFF_CANVAS + SZ_CANVAS;
constexpr size_t OFF_CLV    = OFF_CMU    + SZ_CMU;
constexpr size_t OFF_CDEC   = OFF_CLV    + SZ_CMU;
constexpr size_t OFF_HMUP   = OFF_CDEC   + SZ_CDEC;
constexpr size_t OFF_HLVP   = OFF_HMUP   + SZ_HP;
constexpr size_t OFF_U      = OFF_HLVP   + SZ_HP;
constexpr size_t OFF_U2A    = OFF_U      + SZ_U;
constexpr size_t OFF_U2B    = OFF_U2A    + SZ_U2;
constexpr size_t OFF_END    = OFF_U2B    + SZ_U2;

extern "C" void kernel_launch(void* const* d_in, const int* in_sizes, int n_in,
                              void* d_out, int out_size, void* d_ws, size_t ws_size,
                              hipStream_t stream) {
  const float* x      = (const float*)d_in[0];
  const float* noise  = (const float*)d_in[1];
  const float* Wihmu  = (const float*)d_in[2];
  const float* Whhmu  = (const float*)d_in[3];
  const float* bmu    = (const float*)d_in[4];
  const float* Wihlv  = (const float*)d_in[5];
  const float* Whhlv  = (const float*)d_in[6];
  const float* blv    = (const float*)d_in[7];
  const float* Wmufc  = (const float*)d_in[8];
  const float* bmufc  = (const float*)d_in[9];
  const float* Wlvfc  = (const float*)d_in[10];
  const float* blvfc  = (const float*)d_in[11];
  const float* Wihdec = (const float*)d_in[12];
  const float* Whhdec = (const float*)d_in[13];
  const float* bdec   = (const float*)d_in[14];
  const float* Wwrite = (const float*)d_in[15];
  const float* bwrite = (const float*)d_in[16];
  int T = in_sizes[1] / (B_SZ*NZ);

  if (ws_size < OFF_END) return;

  char* ws = (char*)d_ws;
  unsigned short* wab   = (unsigned short*)(ws + OFF_WAB);
  unsigned short* wenc  = (unsigned short*)(ws + OFF_WENC);
  unsigned short* whh   = (unsigned short*)(ws + OFF_WHH);
  unsigned short* wdec  = (unsigned short*)(ws + OFF_WDEC);
  unsigned short* wwr   = (unsigned short*)(ws + OFF_WWR);
  unsigned short* wfcmu = (unsigned short*)(ws + OFF_WFCMU);
  unsigned short* wfclv = (unsigned short*)(ws + OFF_WFCLV);
  unsigned short* xbf   = (unsigned short*)(ws + OFF_XBF);
  float* g0     = (float*)(ws + OFF_G0);
  float* gpart  = (float*)(ws + OFF_GPART);
  float* canvas = (float*)(ws + OFF_CANVAS);
  float* cmu    = (float*)(ws + OFF_CMU);
  float* clv    = (float*)(ws + OFF_CLV);
  float* cdec   = (float*)(ws + OFF_CDEC);
  unsigned short* hmup = (unsigned short*)(ws + OFF_HMUP);
  unsigned short* hlvp = (unsigned short*)(ws + OFF_HLVP);
  unsigned short* u    = (unsigned short*)(ws + OFF_U);
  unsigned short* u2[2] = { (unsigned short*)(ws + OFF_U2A),
                            (unsigned short*)(ws + OFF_U2B) };

  float* out = (float*)d_out;
  float* outMu = out + (size_t)B_SZ*IMGSZ;
  float* outLv = outMu + (size_t)T*B_SZ*NZ;

  dim3 blk(256);

  k_setup<<<4096, blk, 0, stream>>>(Wihmu, Wihlv, Whhmu, Whhlv, Wmufc, Wlvfc,
                                    Whhdec, Wihdec, Wwrite, x,
                                    wab, wenc, whh, wdec, wwr, wfcmu, wfclv, xbf);
  hipMemsetAsync(ws + OFF_CANVAS, 0, OFF_END - OFF_CANVAS, stream);
  k_uinit<<<(B_SZ*(IMGSZ/4) + 255)/256, blk, 0, stream>>>(u);
  k_g0<<<800, blk, 0, stream>>>(xbf, wab, gpart);
  k_g0red<<<GSZ/256, blk, 0, stream>>>(gpart, g0);

  for (int t = 0; t < T; ++t){
    unsigned short* u2r = u2[t & 1];
    unsigned short* u2w = u2[(t + 1) & 1];
    k_enc<<<1700, blk, 0, stream>>>(u, wenc, hmup, hlvp, whh, gpart);
    k_cell<<<B_SZ, 512, 0, stream>>>(g0, gpart, bmu, blv, cmu, clv, hmup, hlvp,
                                     wfcmu, wfclv, bmufc, blvfc,
                                     noise + (size_t)t*B_SZ*NZ,
                                     outMu + (size_t)t*B_SZ*NZ,
                                     outLv + (size_t)t*B_SZ*NZ, u2r);
    k_dec<<<100, blk, 0, stream>>>(u2r, wdec, bdec, cdec, u, u2w);
    k_write<<<IMGSZ/64, blk, 0, stream>>>(u2w, wwr, bwrite, canvas, u);
  }

  k_final<<<(B_SZ*IMGSZ)/256, blk, 0, stream>>>(canvas, out);
}